// Round 4
// baseline (469.016 us; speedup 1.0000x reference)
//
#include <hip/hip_runtime.h>

#define NN 20000
#define EE 320000
#define RATIO_F 0.18257418583505536f   // 1/sqrt(30)
#define EPS_F 1e-6f
#define SCALE_D4 0.35355339059327373f  // 64^-0.25

typedef _Float16 f16x8 __attribute__((ext_vector_type(8)));
typedef _Float16 f16x4 __attribute__((ext_vector_type(4)));
typedef float f32x4 __attribute__((ext_vector_type(4)));

__device__ __forceinline__ unsigned fenc(float x) {
  unsigned u = __float_as_uint(x);
  return (u & 0x80000000u) ? ~u : (u | 0x80000000u);
}
__device__ __forceinline__ float fdec(unsigned u) {
  return (u & 0x80000000u) ? __uint_as_float(u & 0x7FFFFFFFu) : __uint_as_float(~u);
}
__device__ __forceinline__ void fma4(float* a, float s, float4 b) {
  a[0] = fmaf(s, b.x, a[0]);
  a[1] = fmaf(s, b.y, a[1]);
  a[2] = fmaf(s, b.z, a[2]);
  a[3] = fmaf(s, b.w, a[3]);
}

// =====================================================================
// K0: build fused weight plane (f16) in MFMA B-fragment order.
// Column layout (1024 cols = 64 cts): [0,256)=q  [256,512)=k  [512,768)=v
//   [768,896)=xd_q (head h = cts 48+2h,49+2h; m<30 valid)
//   [896,1024)=xd_k (head h = cts 56+2h,57+2h)
// Fragment: fi = ct*8 + kt (512 f16); lane l=(g*16+cl), elem j holds
// W[k=32*kt+8*g+j][col=ct*16+cl].
// =====================================================================
__global__ __launch_bounds__(256)
void k0_build(const float* __restrict__ Wq, const float* __restrict__ Wk,
              const float* __restrict__ Wv, const float* __restrict__ bq,
              const float* __restrict__ bk, const float* __restrict__ bv,
              const float* __restrict__ proj, const float* __restrict__ tau,
              _Float16* __restrict__ Wf, float* __restrict__ bbig) {
  const int col = blockIdx.x;
  const int i = threadIdx.x;   // k index
  const float s = rsqrtf(tau[0]) * SCALE_D4;
  float val = 0.f, bias = 0.f;
  if (col < 256) {
    val = Wq[col * 256 + i]; bias = bq[col];
  } else if (col < 512) {
    const int c = col - 256;
    val = Wk[c * 256 + i]; bias = bk[c];
  } else if (col < 768) {
    const int c = col - 512;
    val = Wv[c * 256 + i]; bias = bv[c];
  } else {
    const int rr = col - 768;
    const int grp = rr >> 7;             // 0 = q, 1 = k
    const int h = (rr >> 5) & 3, m = rr & 31;
    if (m < 30) {
      const float* W = grp ? Wk : Wq;
      const float* bb = grp ? bk : bq;
      float a = 0.f, ba = 0.f;
#pragma unroll 8
      for (int d = 0; d < 64; ++d) {
        const float pr = proj[m * 64 + d];
        a  = fmaf(pr, W[(h * 64 + d) * 256 + i], a);
        ba = fmaf(pr, bb[h * 64 + d], ba);
      }
      val = s * a; bias = s * ba;
    }
  }
  const int kt = i >> 5, gg = (i >> 3) & 3, j = i & 7;
  const int lane = gg * 16 + (col & 15);
  const size_t off = (size_t)((col >> 4) * 8 + kt) * 512 + lane * 8 + j;
  Wf[off] = (_Float16)val;
  if (i == 0) bbig[col] = bias;
}

// ---- A-fragment loader: 16 rows x 256 K of f32 -> f16 hi + f16 residual ----
__device__ __forceinline__ void load_frags16(const float* __restrict__ p, int g,
                                             f16x8* Ah, f16x8* Al) {
#pragma unroll
  for (int kt = 0; kt < 8; ++kt) {
    const float4 f0 = *(const float4*)(p + kt * 32 + g * 8);
    const float4 f1 = *(const float4*)(p + kt * 32 + g * 8 + 4);
    float ff[8] = {f0.x, f0.y, f0.z, f0.w, f1.x, f1.y, f1.z, f1.w};
    union { _Float16 h[8]; f16x8 v; } hu, lu;
#pragma unroll
    for (int j = 0; j < 8; ++j) {
      const _Float16 hb = (_Float16)ff[j];
      hu.h[j] = hb;
      lu.h[j] = (_Float16)(ff[j] - (float)hb);
    }
    Ah[kt] = hu.v; Al[kt] = lu.v;
  }
}

// =====================================================================
// K1: f16 2-term MFMA GEMM (20000 x 1024 x 256) + fused epilogues.
// 625 blocks x 4 waves; each wave = 16 rows x one 32-ct stream.
//   w0 (rt0), w1 (rt1): QK stream: k cts 16-31 (p0-15), q cts 0-15 (p16-31)
//   w2 (rt0), w3 (rt1): VXD stream: v 32-47 (p0-15), xd_k 56-63 (p16-23),
//                       xd_q 48-55 (p24-31; head 3 held to post-loop)
// B double-buffered in LDS (2 cts = 16KB per buffer), reg-staged,
// one barrier per phase.
// =====================================================================
__global__ __launch_bounds__(256, 2)
void k1_mfma(const float* __restrict__ feat, const float* __restrict__ zin,
             const _Float16* __restrict__ Wf, const float* __restrict__ bbig,
             const float* __restrict__ tau,
             float* __restrict__ qp, float* __restrict__ kbuf,
             _Float16* __restrict__ vh, unsigned* __restrict__ kmaxU) {
  __shared__ __align__(16) _Float16 bstage[2][2][4096];  // [buf][qk/vxd][8KB]
  __shared__ float dlds[2][4][32];                       // [q/k][head][row]

  const int t = threadIdx.x;
  const int w = t >> 6, lane = t & 63;
  const int g = lane >> 4, cl = lane & 15;
  const int qkw = (w >> 1) == 0;     // waves 0,1 = QK stream
  const int rt = w & 1;
  const int rbase = blockIdx.x * 32 + rt * 16;
  const float sc = rsqrtf(tau[0]) * SCALE_D4;
  const float h2 = 0.5f * sc * sc;

  f16x8 Ah[8], Al[8];
  load_frags16((qkw ? feat : zin) + (size_t)(rbase + cl) * 256, g, Ah, Al);

  // prologue: stage phase-0 cts (qk: ct16, vxd: ct32) into buf 0
#pragma unroll
  for (int i = 0; i < 4; ++i) {
    const int slot = i >> 1, wi = (i & 1) * 256 + t;
    const int ct = slot ? 32 : 16;
    *(uint4*)&bstage[0][slot][wi * 8] = *(const uint4*)(Wf + (size_t)ct * 4096 + wi * 8);
  }
  __syncthreads();

  float ds[4];
  f32x4 aA, heldA, heldB;

  for (int p = 0; p < 32; ++p) {
    const int cur = p & 1;
    uint4 stg[4];
    if (p < 31) {  // issue next-phase B loads early (hide under MFMA)
      const int pn = p + 1;
      const int ctq = (pn < 16) ? 16 + pn : pn - 16;
      const int ctv = (pn < 16) ? 32 + pn : ((pn < 24) ? 40 + pn : 24 + pn);
#pragma unroll
      for (int i = 0; i < 4; ++i) {
        const int slot = i >> 1, wi = (i & 1) * 256 + t;
        const int ct = slot ? ctv : ctq;
        stg[i] = *(const uint4*)(Wf + (size_t)ct * 4096 + wi * 8);
      }
    }
    if (!qkw && p == 16)  // VXD switches A from z to feat for xd phases
      load_frags16(feat + (size_t)(rbase + cl) * 256, g, Ah, Al);

    const int ct = qkw ? ((p < 16) ? 16 + p : p - 16)
                       : ((p < 16) ? 32 + p : ((p < 24) ? 40 + p : 24 + p));
    const _Float16* bp = &bstage[cur][qkw ? 0 : 1][0];
    f16x8 bfr[8];
#pragma unroll
    for (int kt = 0; kt < 8; ++kt)
      bfr[kt] = *(const f16x8*)(bp + kt * 512 + lane * 8);
    f32x4 a0 = {0.f, 0.f, 0.f, 0.f}, a1 = {0.f, 0.f, 0.f, 0.f};
#pragma unroll
    for (int kt = 0; kt < 8; ++kt) {
      a0 = __builtin_amdgcn_mfma_f32_16x16x32_f16(Ah[kt], bfr[kt], a0, 0, 0, 0);
      a1 = __builtin_amdgcn_mfma_f32_16x16x32_f16(Al[kt], bfr[kt], a1, 0, 0, 0);
    }
    const float bb = bbig[ct * 16 + cl];
    f32x4 a;
#pragma unroll
    for (int j = 0; j < 4; ++j) a[j] = a0[j] + a1[j] + bb;

    if (qkw) {
      // ---- q/k: row sum-of-squares over the head's 4 cts -> diag ----
      const int sub = p & 3, qki = (p < 16) ? 1 : 0, h = (p & 15) >> 2;
#pragma unroll
      for (int j = 0; j < 4; ++j) {
        const float v = a[j];
        ds[j] = sub ? fmaf(v, v, ds[j]) : v * v;
      }
      if (sub == 3) {
#pragma unroll
        for (int j = 0; j < 4; ++j) {
          float v2 = ds[j];
#pragma unroll
          for (int m = 1; m < 16; m <<= 1) v2 += __shfl_xor(v2, m);
          if (cl == 0) dlds[qki][h][rt * 16 + 4 * g + j] = h2 * v2;
        }
      }
    } else if (p < 16) {
      // ---- v: bias + f16 store ----
      const int colb = (ct - 32) * 16 + cl;
#pragma unroll
      for (int j = 0; j < 4; ++j)
        vh[(size_t)(rbase + 4 * g + j) * 256 + colb] = (_Float16)a[j];
    } else {
      // ---- xd: pairs of cts per head ----
      const int idx = p - 16, qki = (idx < 8) ? 1 : 0;
      const int h = (idx >> 1) & 3, sub = idx & 1;
      if (!sub) {
        aA = a;
      } else if (qki == 0 && h == 3) {
        heldA = aA; heldB = a;     // diag_q[3] not ready yet
      } else {
        float wmax = -3.4e38f;
#pragma unroll
        for (int j = 0; j < 4; ++j) {
          float mv = fmaxf(aA[j], (cl < 14) ? a[j] : -3.4e38f);
#pragma unroll
          for (int m = 1; m < 16; m <<= 1) mv = fmaxf(mv, __shfl_xor(mv, m));
          const float dg = dlds[qki][h][rt * 16 + 4 * g + j];
          const int r = rbase + 4 * g + j;
          if (qki) {
            wmax = fmaxf(wmax, mv);
            float* dst = kbuf + (size_t)r * 120 + h * 30;
            dst[cl] = aA[j] - dg;
            if (cl < 14) dst[16 + cl] = a[j] - dg;
          } else {
            float* dst = qp + (size_t)r * 120 + h * 30;
            dst[cl] = RATIO_F * (expf(aA[j] - dg - mv) + EPS_F);
            if (cl < 14) dst[16 + cl] = RATIO_F * (expf(a[j] - dg - mv) + EPS_F);
          }
        }
        if (qki) {
          wmax = fmaxf(wmax, __shfl_xor(wmax, 16));
          wmax = fmaxf(wmax, __shfl_xor(wmax, 32));
          if (lane == 0) atomicMax(&kmaxU[h], fenc(wmax));
        }
      }
    }
    if (p < 31) {
#pragma unroll
      for (int i = 0; i < 4; ++i) {
        const int slot = i >> 1, wi = (i & 1) * 256 + t;
        *(uint4*)&bstage[cur ^ 1][slot][wi * 8] = stg[i];
      }
    }
    __syncthreads();
  }

  if (!qkw) {  // finish held xd_q head 3 (diag_q[3] ready after p31 barrier)
#pragma unroll
    for (int j = 0; j < 4; ++j) {
      float mv = fmaxf(heldA[j], (cl < 14) ? heldB[j] : -3.4e38f);
#pragma unroll
      for (int m = 1; m < 16; m <<= 1) mv = fmaxf(mv, __shfl_xor(mv, m));
      const float dg = dlds[0][3][rt * 16 + 4 * g + j];
      const int r = rbase + 4 * g + j;
      float* dst = qp + (size_t)r * 120 + 3 * 30;
      dst[cl] = RATIO_F * (expf(heldA[j] - dg - mv) + EPS_F);
      if (cl < 14) dst[16 + cl] = RATIO_F * (expf(heldB[j] - dg - mv) + EPS_F);
    }
  }
}

// ------------- K3: kvs[h,m,d] = sum_n kp*v; ksum[h,m] = sum_n kp (kp inline) -------------
__global__ __launch_bounds__(256)
void k3_kvs(const float* __restrict__ kbr, const _Float16* __restrict__ vh,
            const unsigned* __restrict__ kmaxU,
            float* __restrict__ kvs, float* __restrict__ ksum) {
  __shared__ float kpch[128 * 32];
  __shared__ float vch[128 * 68];
  const int h = blockIdx.y;
  const int n0 = blockIdx.x * 128;
  const int cnt = min(128, NN - n0);
  const int t = threadIdx.x;
  const float mx = fdec(kmaxU[h]);
  const int m = t >> 3, dg = t & 7, d0 = dg * 8;
#pragma unroll
  for (int l = 0; l < 15; ++l) {
    const int flat = l * 256 + t;
    const int nl = flat / 30, mm = flat - nl * 30;
    kpch[nl * 32 + mm] = (nl < cnt)
        ? RATIO_F * (expf(kbr[(size_t)(n0 + nl) * 120 + h * 30 + mm] - mx) + EPS_F)
        : 0.f;
  }
#pragma unroll
  for (int l = 0; l < 8; ++l) {
    const int f4 = l * 256 + t;
    const int nl = f4 >> 4, dd = (f4 & 15) * 4;
    float4 vv = make_float4(0.f, 0.f, 0.f, 0.f);
    if (nl < cnt) {
      f16x4 u = *(const f16x4*)(vh + (size_t)(n0 + nl) * 256 + h * 64 + dd);
      vv = make_float4((float)u[0], (float)u[1], (float)u[2], (float)u[3]);
    }
    *(float4*)&vch[nl * 68 + dd] = vv;
  }
  __syncthreads();
  float acc[8] = {0, 0, 0, 0, 0, 0, 0, 0};
  float asum = 0.f;
  const int ms = (m < 30) ? m : 0;
  for (int nl = 0; nl < cnt; ++nl) {
    const float kv = kpch[nl * 32 + ms];
    const float4 va = *(const float4*)&vch[nl * 68 + d0];
    const float4 vb = *(const float4*)&vch[nl * 68 + d0 + 4];
    fma4(&acc[0], kv, va);
    fma4(&acc[4], kv, vb);
    asum += kv;
  }
  if (m < 30) {
    float* dst = kvs + (size_t)(h * 30 + m) * 64 + d0;
#pragma unroll
    for (int j = 0; j < 8; ++j) atomicAdd(dst + j, acc[j]);
    if (dg == 0) atomicAdd(ksum + h * 30 + m, asum);
  }
}

// ------------- K4: num/den + fused relational-bias gather -> zbuf -------------
__global__ __launch_bounds__(256)
void k4_attn(const float* __restrict__ qp, const float* __restrict__ kvs,
             const float* __restrict__ ksum, const int* __restrict__ coff,
             const int* __restrict__ crow, const int* __restrict__ douti,
             const _Float16* __restrict__ vh, const float* __restrict__ bp,
             float* __restrict__ zbuf) {
  __shared__ float kvsl[120 * 68];
  __shared__ float ksl[120];
  __shared__ float qpl[32 * 120];
  const int t = threadIdx.x;
  const int n0 = blockIdx.x * 32;
#pragma unroll
  for (int l = 0; l < 30; ++l) {
    const int f = l * 256 + t;           // 7680
    const int hm = f >> 6, d = f & 63;
    kvsl[hm * 68 + d] = kvs[f];
  }
  if (t < 120) ksl[t] = ksum[t];
#pragma unroll
  for (int l = 0; l < 15; ++l) {
    const int f = l * 256 + t;           // 3840
    qpl[f] = qp[(size_t)n0 * 120 + f];
  }
  __syncthreads();
  const int nl = t >> 3, dg = t & 7, d0 = dg * 8;
  const float* qrow = &qpl[nl * 120];
  float den[4] = {0, 0, 0, 0};
  for (int m = 0; m < 30; ++m) {
#pragma unroll
    for (int hh = 0; hh < 4; ++hh) den[hh] = fmaf(qrow[hh * 30 + m], ksl[hh * 30 + m], den[hh]);
  }
  float acc[4][8] = {};
  for (int m = 0; m < 30; ++m) {
#pragma unroll
    for (int hh = 0; hh < 4; ++hh) {
      const float qv = qrow[hh * 30 + m];
      const float* kr = &kvsl[(hh * 30 + m) * 68 + d0];
      const float4 ka = *(const float4*)kr;
      const float4 kb = *(const float4*)(kr + 4);
      fma4(&acc[hh][0], qv, ka);
      fma4(&acc[hh][4], qv, kb);
    }
  }
  // ---- fused gather (was k7): agg over CSR-by-col edges ----
  const int node = n0 + nl;
  const int o0 = coff[node], o1 = coff[node + 1];
  float gg[4][8] = {};
  if (o1 > o0) {
    const float rin = rsqrtf((float)(o1 - o0));
    for (int e = o0; e < o1; ++e) {
      const int r = crow[e];
      const float wgt = rin * rsqrtf((float)douti[r]);
#pragma unroll
      for (int hh = 0; hh < 4; ++hh) {
        const f16x8 vv = *(const f16x8*)(vh + (size_t)r * 256 + hh * 64 + d0);
#pragma unroll
        for (int jj = 0; jj < 8; ++jj)
          gg[hh][jj] = fmaf(wgt, (float)vv[jj], gg[hh][jj]);
      }
    }
  }
  const size_t n = node;
#pragma unroll
  for (int hh = 0; hh < 4; ++hh) {
    const float inv = 1.0f / den[hh];
    const float sg = 1.f / (1.f + expf(-bp[hh]));
    float o[8];
#pragma unroll
    for (int jj = 0; jj < 8; ++jj) o[jj] = acc[hh][jj] * inv + sg * gg[hh][jj];
    *(float4*)(zbuf + n * 256 + hh * 64 + d0) = make_float4(o[0], o[1], o[2], o[3]);
    *(float4*)(zbuf + n * 256 + hh * 64 + d0 + 4) = make_float4(o[4], o[5], o[6], o[7]);
  }
}

// ------------- K5: degree counts (int4 vectorized) -------------
__global__ __launch_bounds__(256)
void k5_deg(const int* __restrict__ ei, int* __restrict__ dini, int* __restrict__ douti) {
  const int q = blockIdx.x * 256 + threadIdx.x;
  if (q >= EE / 4) return;
  const int4 r4 = *(const int4*)(ei + q * 4);
  const int4 c4 = *(const int4*)(ei + EE + q * 4);
  atomicAdd(&dini[c4.x], 1); atomicAdd(&dini[c4.y], 1);
  atomicAdd(&dini[c4.z], 1); atomicAdd(&dini[c4.w], 1);
  atomicAdd(&douti[r4.x], 1); atomicAdd(&douti[r4.y], 1);
  atomicAdd(&douti[r4.z], 1); atomicAdd(&douti[r4.w], 1);
}

// ------------- K6a: exclusive scan of in-degrees (1024 threads, int4) -------------
__global__ __launch_bounds__(1024)
void k6a_scan(const int* __restrict__ cnt, int* __restrict__ off) {
  __shared__ int s[1024];
  const int t = threadIdx.x;
  int4 v[5];
  int sum = 0;
  const int4* p4 = (const int4*)(cnt + t * 20);
#pragma unroll
  for (int i = 0; i < 5; ++i) {
    v[i] = p4[i];
    sum += v[i].x + v[i].y + v[i].z + v[i].w;
  }
  s[t] = sum;
  __syncthreads();
  for (int o = 1; o < 1024; o <<= 1) {
    const int add = (t >= o) ? s[t - o] : 0;
    __syncthreads();
    s[t] += add;
    __syncthreads();
  }
  int run = (t == 0) ? 0 : s[t - 1];
  if (t == 0) off[0] = 0;
  const int base = t * 20;
#pragma unroll
  for (int i = 0; i < 5; ++i) {
    const int vals[4] = {v[i].x, v[i].y, v[i].z, v[i].w};
#pragma unroll
    for (int j = 0; j < 4; ++j) {
      const int idx = base + i * 4 + j;
      if (idx < NN) { run += vals[j]; off[idx + 1] = run; }
    }
  }
}

// ------------- K6b: fill CSR (rows bucketed by col) -------------
__global__ __launch_bounds__(256)
void k6b_fill(const int* __restrict__ ei, const int* __restrict__ coff,
              int* __restrict__ cursor, int* __restrict__ crow) {
  const int e = blockIdx.x * 256 + threadIdx.x;
  const int r = ei[e], c = ei[EE + e];
  const int pos = atomicAdd(&cursor[c], 1);
  crow[coff[c] + pos] = r;
}

// ------------- K8: out = zbuf @ Wo^T + bo -------------
__global__ __launch_bounds__(256)
void k8_out(const float* __restrict__ zbuf, const float* __restrict__ Wo,
            const float* __restrict__ bo, float* __restrict__ out) {
  __shared__ float WoT[256 * 33];
  __shared__ float zbl[8 * 256];
  const int t = threadIdx.x;
  const int ch = blockIdx.y;  // 0/1 -> output cols [ch*32, ch*32+32)
#pragma unroll
  for (int l = 0; l < 32; ++l) {
    WoT[t * 33 + l] = Wo[(ch * 32 + l) * 256 + t];
  }
  const int nl = t >> 5, cp = t & 31;
  const float bias = bo[ch * 32 + cp];
  for (int g = blockIdx.x; g < 2500; g += gridDim.x) {
    __syncthreads();
#pragma unroll
    for (int l = 0; l < 2; ++l) {
      const int f4 = l * 256 + t;
      *(float4*)&zbl[f4 * 4] = *(const float4*)(zbuf + (size_t)g * 2048 + f4 * 4);
    }
    __syncthreads();
    float acc = bias;
#pragma unroll
    for (int i4 = 0; i4 < 64; ++i4) {
      const float4 z4 = *(const float4*)&zbl[nl * 256 + i4 * 4];
      acc = fmaf(z4.x, WoT[(i4 * 4 + 0) * 33 + cp], acc);
      acc = fmaf(z4.y, WoT[(i4 * 4 + 1) * 33 + cp], acc);
      acc = fmaf(z4.z, WoT[(i4 * 4 + 2) * 33 + cp], acc);
      acc = fmaf(z4.w, WoT[(i4 * 4 + 3) * 33 + cp], acc);
    }
    out[((size_t)g * 8 + nl) * 64 + ch * 32 + cp] = acc;
  }
}

extern "C" void kernel_launch(void* const* d_in, const int* in_sizes, int n_in,
                              void* d_out, int out_size, void* d_ws, size_t ws_size,
                              hipStream_t stream) {
  (void)in_sizes; (void)n_in; (void)out_size; (void)ws_size;
  const float* z    = (const float*)d_in[0];
  const float* feat = (const float*)d_in[1];
  const int*   ei   = (const int*)d_in[2];
  const float* tau  = (const float*)d_in[3];
  const float* Wq_w = (const float*)d_in[4];
  const float* Wq_b = (const float*)d_in[5];
  const float* Wk_w = (const float*)d_in[6];
  const float* Wk_b = (const float*)d_in[7];
  const float* Wv_w = (const float*)d_in[8];
  const float* Wv_b = (const float*)d_in[9];
  const float* Wo_w = (const float*)d_in[10];
  const float* Wo_b = (const float*)d_in[11];
  const float* bp   = (const float*)d_in[12];
  const float* proj = (const float*)d_in[13];
  float* out = (float*)d_out;

  char* p = (char*)d_ws;
  auto alloc = [&](size_t bytes) { char* r = p; p += (bytes + 255) & ~(size_t)255; return r; };
  _Float16* Wf    = (_Float16*)alloc((size_t)256 * 1024 * 2);
  float*    bbig  = (float*)alloc(1024 * 4);
  _Float16* vh    = (_Float16*)alloc((size_t)NN * 256 * 2);
  float*    qp    = (float*)alloc((size_t)NN * 120 * 4);
  float*    kbuf  = (float*)alloc((size_t)NN * 120 * 4);
  float*    zbuf  = (float*)alloc((size_t)NN * 256 * 4);
  // ---- contiguous zero-region ----
  char* z0 = p;
  float*    kvs   = (float*)alloc(7680 * 4);
  float*    ksum  = (float*)alloc(120 * 4);
  unsigned* kmaxU = (unsigned*)alloc(16);
  int*      dini  = (int*)alloc((size_t)20480 * 4);   // padded for int4 scan
  int*      douti = (int*)alloc((size_t)NN * 4);
  int*      cursor= (int*)alloc((size_t)NN * 4);
  char* z1 = p;
  int*      coff  = (int*)alloc((size_t)(NN + 1) * 4);
  int*      crow  = (int*)alloc((size_t)EE * 4);

  hipMemsetAsync(z0, 0, (size_t)(z1 - z0), stream);

  k0_build<<<1024, 256, 0, stream>>>(Wq_w, Wk_w, Wv_w, Wq_b, Wk_b, Wv_b, proj, tau, Wf, bbig);
  k5_deg<<<(EE / 4 + 255) / 256, 256, 0, stream>>>(ei, dini, douti);
  k6a_scan<<<1, 1024, 0, stream>>>(dini, coff);
  k6b_fill<<<EE / 256, 256, 0, stream>>>(ei, coff, cursor, crow);
  k1_mfma<<<625, 256, 0, stream>>>(feat, z, Wf, bbig, tau, qp, kbuf, vh, kmaxU);
  k3_kvs<<<dim3((NN + 127) / 128, 4), 256, 0, stream>>>(kbuf, vh, kmaxU, kvs, ksum);
  k4_attn<<<NN / 32, 256, 0, stream>>>(qp, kvs, ksum, coff, crow, douti, vh, bp, zbuf);
  k8_out<<<dim3(512, 2), 256, 0, stream>>>(zbuf, Wo_w, Wo_b, out);
}

// Round 5
// 318.384 us; speedup vs baseline: 1.4731x; 1.4731x over previous
//
#include <hip/hip_runtime.h>

#define NN 20000
#define EE 320000
#define RATIO_F 0.18257418583505536f   // 1/sqrt(30)
#define EPS_F 1e-6f
#define SCALE_D4 0.35355339059327373f  // 64^-0.25
#define NCH 157                        // ceil(20000/128) k3 chunks

typedef _Float16 f16x8 __attribute__((ext_vector_type(8)));
typedef _Float16 f16x4 __attribute__((ext_vector_type(4)));
typedef float f32x4 __attribute__((ext_vector_type(4)));

__device__ __forceinline__ unsigned fenc(float x) {
  unsigned u = __float_as_uint(x);
  return (u & 0x80000000u) ? ~u : (u | 0x80000000u);
}
__device__ __forceinline__ float fdec(unsigned u) {
  return (u & 0x80000000u) ? __uint_as_float(u & 0x7FFFFFFFu) : __uint_as_float(~u);
}
__device__ __forceinline__ void fma4(float* a, float s, float4 b) {
  a[0] = fmaf(s, b.x, a[0]);
  a[1] = fmaf(s, b.y, a[1]);
  a[2] = fmaf(s, b.z, a[2]);
  a[3] = fmaf(s, b.w, a[3]);
}

// =====================================================================
// K0: build fused weight plane (f16) in MFMA B-fragment order.
// Columns (1024 = 64 cts): [0,256)=q  [256,512)=k  [512,768)=v
//   xd_q head h = cts 48+2h,49+2h (m<30 valid); xd_k head h = cts 56+2h,57+2h
// Fragment fi = ct*8+kt (512 f16); lane l=(g*16+cl), elem j holds
// W[k=32*kt+8*g+j][col=ct*16+cl].
// =====================================================================
__global__ __launch_bounds__(256)
void k0_build(const float* __restrict__ Wq, const float* __restrict__ Wk,
              const float* __restrict__ Wv, const float* __restrict__ bq,
              const float* __restrict__ bk, const float* __restrict__ bv,
              const float* __restrict__ proj, const float* __restrict__ tau,
              _Float16* __restrict__ Wf, float* __restrict__ bbig) {
  const int col = blockIdx.x;
  const int i = threadIdx.x;   // k index
  const float s = rsqrtf(tau[0]) * SCALE_D4;
  float val = 0.f, bias = 0.f;
  if (col < 256) {
    val = Wq[col * 256 + i]; bias = bq[col];
  } else if (col < 512) {
    const int c = col - 256;
    val = Wk[c * 256 + i]; bias = bk[c];
  } else if (col < 768) {
    const int c = col - 512;
    val = Wv[c * 256 + i]; bias = bv[c];
  } else {
    const int rr = col - 768;
    const int grp = rr >> 7;             // 0 = q, 1 = k
    const int h = (rr >> 5) & 3, m = rr & 31;
    if (m < 30) {
      const float* W = grp ? Wk : Wq;
      const float* bb = grp ? bk : bq;
      float a = 0.f, ba = 0.f;
#pragma unroll 8
      for (int d = 0; d < 64; ++d) {
        const float pr = proj[m * 64 + d];
        a  = fmaf(pr, W[(h * 64 + d) * 256 + i], a);
        ba = fmaf(pr, bb[h * 64 + d], ba);
      }
      val = s * a; bias = s * ba;
    }
  }
  const int kt = i >> 5, gg = (i >> 3) & 3, j = i & 7;
  const int lane = gg * 16 + (col & 15);
  const size_t off = (size_t)((col >> 4) * 8 + kt) * 512 + lane * 8 + j;
  Wf[off] = (_Float16)val;
  if (i == 0) bbig[col] = bias;
}

// ---- A-fragment loader: 16 rows x 256 K of f32 -> f16 hi + f16 residual ----
__device__ __forceinline__ void load_frags16(const float* __restrict__ p, int g,
                                             f16x8* Ah, f16x8* Al) {
#pragma unroll
  for (int kt = 0; kt < 8; ++kt) {
    const float4 f0 = *(const float4*)(p + kt * 32 + g * 8);
    const float4 f1 = *(const float4*)(p + kt * 32 + g * 8 + 4);
    float ff[8] = {f0.x, f0.y, f0.z, f0.w, f1.x, f1.y, f1.z, f1.w};
    union { _Float16 h[8]; f16x8 v; } hu, lu;
#pragma unroll
    for (int j = 0; j < 8; ++j) {
      const _Float16 hb = (_Float16)ff[j];
      hu.h[j] = hb;
      lu.h[j] = (_Float16)(ff[j] - (float)hb);
    }
    Ah[kt] = hu.v; Al[kt] = lu.v;
  }
}

// ---- one 16x16 C-tile over K=256: B from global (L2-hot), 2-term A ----
__device__ __forceinline__ f32x4 ct_mfma(const _Float16* __restrict__ Wf,
                                         const float* __restrict__ bbig,
                                         int ct, int lane, int cl,
                                         const f16x8* Ah, const f16x8* Al) {
  f16x8 bfr[8];
#pragma unroll
  for (int kt = 0; kt < 8; ++kt)
    bfr[kt] = *(const f16x8*)(Wf + (size_t)ct * 4096 + kt * 512 + lane * 8);
  f32x4 a0 = {0.f, 0.f, 0.f, 0.f}, a1 = {0.f, 0.f, 0.f, 0.f};
#pragma unroll
  for (int kt = 0; kt < 8; ++kt) {
    a0 = __builtin_amdgcn_mfma_f32_16x16x32_f16(Ah[kt], bfr[kt], a0, 0, 0, 0);
    a1 = __builtin_amdgcn_mfma_f32_16x16x32_f16(Al[kt], bfr[kt], a1, 0, 0, 0);
  }
  const float bb = bbig[ct * 16 + cl];
  f32x4 r;
#pragma unroll
  for (int j = 0; j < 4; ++j) r[j] = a0[j] + a1[j] + bb;
  return r;
}

// =====================================================================
// K1a: q/k/xd for one head per wave. 16 rows/block, 4 waves = 4 heads.
// Zero LDS, zero barriers: diag + row-max + exp all wave-local.
// =====================================================================
__global__ __launch_bounds__(256, 2)
void k1_qk(const float* __restrict__ feat, const _Float16* __restrict__ Wf,
           const float* __restrict__ bbig, const float* __restrict__ tau,
           float* __restrict__ qp, float* __restrict__ kbuf,
           unsigned* __restrict__ kmaxU) {
  const int t = threadIdx.x;
  const int h = t >> 6, lane = t & 63;
  const int g = lane >> 4, cl = lane & 15;
  const int rbase = blockIdx.x * 16;
  const float sc = rsqrtf(tau[0]) * SCALE_D4;
  const float h2 = 0.5f * sc * sc;

  f16x8 Ah[8], Al[8];
  load_frags16(feat + (size_t)(rbase + cl) * 256, g, Ah, Al);

  float dsq[4] = {0.f, 0.f, 0.f, 0.f}, dsk[4] = {0.f, 0.f, 0.f, 0.f};
#pragma unroll 2
  for (int c4 = 0; c4 < 4; ++c4) {
    const f32x4 a = ct_mfma(Wf, bbig, h * 4 + c4, lane, cl, Ah, Al);
#pragma unroll
    for (int j = 0; j < 4; ++j) dsq[j] = fmaf(a[j], a[j], dsq[j]);
  }
#pragma unroll 2
  for (int c4 = 0; c4 < 4; ++c4) {
    const f32x4 a = ct_mfma(Wf, bbig, 16 + h * 4 + c4, lane, cl, Ah, Al);
#pragma unroll
    for (int j = 0; j < 4; ++j) dsk[j] = fmaf(a[j], a[j], dsk[j]);
  }
#pragma unroll
  for (int m = 1; m < 16; m <<= 1) {
#pragma unroll
    for (int j = 0; j < 4; ++j) {
      dsq[j] += __shfl_xor(dsq[j], m);
      dsk[j] += __shfl_xor(dsk[j], m);
    }
  }
  {  // ---- xd_q -> qp ----
    const f32x4 x0 = ct_mfma(Wf, bbig, 48 + 2 * h, lane, cl, Ah, Al);
    const f32x4 x1 = ct_mfma(Wf, bbig, 49 + 2 * h, lane, cl, Ah, Al);
#pragma unroll
    for (int j = 0; j < 4; ++j) {
      float mv = fmaxf(x0[j], (cl < 14) ? x1[j] : -3.4e38f);
#pragma unroll
      for (int m = 1; m < 16; m <<= 1) mv = fmaxf(mv, __shfl_xor(mv, m));
      const float dg = h2 * dsq[j];
      float* dst = qp + (size_t)(rbase + 4 * g + j) * 120 + h * 30;
      dst[cl] = RATIO_F * (expf(x0[j] - dg - mv) + EPS_F);
      if (cl < 14) dst[16 + cl] = RATIO_F * (expf(x1[j] - dg - mv) + EPS_F);
    }
  }
  {  // ---- xd_k -> kbuf + global head max ----
    const f32x4 x0 = ct_mfma(Wf, bbig, 56 + 2 * h, lane, cl, Ah, Al);
    const f32x4 x1 = ct_mfma(Wf, bbig, 57 + 2 * h, lane, cl, Ah, Al);
    float wmax = -3.4e38f;
#pragma unroll
    for (int j = 0; j < 4; ++j) {
      float mv = fmaxf(x0[j], (cl < 14) ? x1[j] : -3.4e38f);
#pragma unroll
      for (int m = 1; m < 16; m <<= 1) mv = fmaxf(mv, __shfl_xor(mv, m));
      wmax = fmaxf(wmax, mv);
      const float dg = h2 * dsk[j];
      float* dst = kbuf + (size_t)(rbase + 4 * g + j) * 120 + h * 30;
      dst[cl] = x0[j] - dg;
      if (cl < 14) dst[16 + cl] = x1[j] - dg;
    }
    wmax = fmaxf(wmax, __shfl_xor(wmax, 16));
    wmax = fmaxf(wmax, __shfl_xor(wmax, 32));
    if (lane == 0) atomicMax(&kmaxU[h], fenc(wmax));
  }
}

// =====================================================================
// K1b: v = z @ Wv (+bias) -> f16. Wave = 16 rows x 8 cts. No LDS/barriers.
// =====================================================================
__global__ __launch_bounds__(256, 2)
void k1_v(const float* __restrict__ zin, const _Float16* __restrict__ Wf,
          const float* __restrict__ bbig, _Float16* __restrict__ vh) {
  const int t = threadIdx.x;
  const int w = t >> 6, lane = t & 63;
  const int g = lane >> 4, cl = lane & 15;
  const int rt = w >> 1, half = w & 1;
  const int rbase = blockIdx.x * 32 + rt * 16;
  f16x8 Ah[8], Al[8];
  load_frags16(zin + (size_t)(rbase + cl) * 256, g, Ah, Al);
#pragma unroll 2
  for (int c = 0; c < 8; ++c) {
    const int ct = 32 + half * 8 + c;
    const f32x4 a = ct_mfma(Wf, bbig, ct, lane, cl, Ah, Al);
    const int colb = (ct - 32) * 16 + cl;
#pragma unroll
    for (int j = 0; j < 4; ++j)
      vh[(size_t)(rbase + 4 * g + j) * 256 + colb] = (_Float16)a[j];
  }
}

// ------------- K3a: per-chunk partials of kvs/ksum (no atomics) -------------
__global__ __launch_bounds__(256)
void k3_kvs(const float* __restrict__ kbr, const _Float16* __restrict__ vh,
            const unsigned* __restrict__ kmaxU, float* __restrict__ partial) {
  __shared__ float kpch[128 * 32];
  __shared__ float vch[128 * 68];
  const int h = blockIdx.y;
  const int n0 = blockIdx.x * 128;
  const int cnt = min(128, NN - n0);
  const int t = threadIdx.x;
  const float mx = fdec(kmaxU[h]);
  const int m = t >> 3, dg = t & 7, d0 = dg * 8;
#pragma unroll
  for (int l = 0; l < 15; ++l) {
    const int flat = l * 256 + t;
    const int nl = flat / 30, mm = flat - nl * 30;
    kpch[nl * 32 + mm] = (nl < cnt)
        ? RATIO_F * (expf(kbr[(size_t)(n0 + nl) * 120 + h * 30 + mm] - mx) + EPS_F)
        : 0.f;
  }
#pragma unroll
  for (int l = 0; l < 8; ++l) {
    const int f4 = l * 256 + t;
    const int nl = f4 >> 4, dd = (f4 & 15) * 4;
    float4 vv = make_float4(0.f, 0.f, 0.f, 0.f);
    if (nl < cnt) {
      f16x4 u = *(const f16x4*)(vh + (size_t)(n0 + nl) * 256 + h * 64 + dd);
      vv = make_float4((float)u[0], (float)u[1], (float)u[2], (float)u[3]);
    }
    *(float4*)&vch[nl * 68 + dd] = vv;
  }
  __syncthreads();
  float acc[8] = {0, 0, 0, 0, 0, 0, 0, 0};
  float asum = 0.f;
  const int ms = (m < 30) ? m : 0;
  for (int nl = 0; nl < cnt; ++nl) {
    const float kv = kpch[nl * 32 + ms];
    const float4 va = *(const float4*)&vch[nl * 68 + d0];
    const float4 vb = *(const float4*)&vch[nl * 68 + d0 + 4];
    fma4(&acc[0], kv, va);
    fma4(&acc[4], kv, vb);
    asum += kv;
  }
  if (m < 30) {
    float* dst = partial + ((size_t)blockIdx.y * NCH + blockIdx.x) * 1952 + m * 64 + d0;
#pragma unroll
    for (int j = 0; j < 8; ++j) dst[j] = acc[j];
    if (dg == 0)
      partial[((size_t)blockIdx.y * NCH + blockIdx.x) * 1952 + 1920 + m] = asum;
  }
}

// ------------- K3b: reduce partials -> kvs, ksum -------------
__global__ __launch_bounds__(256)
void k3b_reduce(const float* __restrict__ partial, float* __restrict__ kvs,
                float* __restrict__ ksum) {
  const int idx = blockIdx.x * 256 + threadIdx.x;
  if (idx >= 4 * 1952) return;
  const int h = idx / 1952, q = idx - h * 1952;
  float s = 0.f;
  for (int c = 0; c < NCH; ++c)
    s += partial[((size_t)h * NCH + c) * 1952 + q];
  if (q < 1920) kvs[h * 1920 + q] = s;
  else if (q < 1950) ksum[h * 30 + (q - 1920)] = s;
}

// ------------- K4: num/den -> zbuf -------------
__global__ __launch_bounds__(256)
void k4_attn(const float* __restrict__ qp, const float* __restrict__ kvs,
             const float* __restrict__ ksum, float* __restrict__ zbuf) {
  __shared__ float kvsl[120 * 68];
  __shared__ float ksl[120];
  __shared__ float qpl[32 * 120];
  const int t = threadIdx.x;
  const int n0 = blockIdx.x * 32;
#pragma unroll
  for (int l = 0; l < 30; ++l) {
    const int f = l * 256 + t;           // 7680
    const int hm = f >> 6, d = f & 63;
    kvsl[hm * 68 + d] = kvs[f];
  }
  if (t < 120) ksl[t] = ksum[t];
#pragma unroll
  for (int l = 0; l < 15; ++l) {
    const int f = l * 256 + t;           // 3840
    qpl[f] = qp[(size_t)n0 * 120 + f];
  }
  __syncthreads();
  const int nl = t >> 3, dg = t & 7, d0 = dg * 8;
  const float* qrow = &qpl[nl * 120];
  float den[4] = {0, 0, 0, 0};
  for (int m = 0; m < 30; ++m) {
#pragma unroll
    for (int hh = 0; hh < 4; ++hh) den[hh] = fmaf(qrow[hh * 30 + m], ksl[hh * 30 + m], den[hh]);
  }
  float acc[4][8] = {};
  for (int m = 0; m < 30; ++m) {
#pragma unroll
    for (int hh = 0; hh < 4; ++hh) {
      const float qv = qrow[hh * 30 + m];
      const float* kr = &kvsl[(hh * 30 + m) * 68 + d0];
      const float4 ka = *(const float4*)kr;
      const float4 kb = *(const float4*)(kr + 4);
      fma4(&acc[hh][0], qv, ka);
      fma4(&acc[hh][4], qv, kb);
    }
  }
  const size_t n = n0 + nl;
#pragma unroll
  for (int hh = 0; hh < 4; ++hh) {
    const float inv = 1.0f / den[hh];
    float4 o1 = make_float4(acc[hh][0] * inv, acc[hh][1] * inv, acc[hh][2] * inv, acc[hh][3] * inv);
    float4 o2 = make_float4(acc[hh][4] * inv, acc[hh][5] * inv, acc[hh][6] * inv, acc[hh][7] * inv);
    *(float4*)(zbuf + n * 256 + hh * 64 + d0) = o1;
    *(float4*)(zbuf + n * 256 + hh * 64 + d0 + 4) = o2;
  }
}

// ------------- K5: degree counts (int4 vectorized) -------------
__global__ __launch_bounds__(256)
void k5_deg(const int* __restrict__ ei, int* __restrict__ dini, int* __restrict__ douti) {
  const int q = blockIdx.x * 256 + threadIdx.x;
  if (q >= EE / 4) return;
  const int4 r4 = *(const int4*)(ei + q * 4);
  const int4 c4 = *(const int4*)(ei + EE + q * 4);
  atomicAdd(&dini[c4.x], 1); atomicAdd(&dini[c4.y], 1);
  atomicAdd(&dini[c4.z], 1); atomicAdd(&dini[c4.w], 1);
  atomicAdd(&douti[r4.x], 1); atomicAdd(&douti[r4.y], 1);
  atomicAdd(&douti[r4.z], 1); atomicAdd(&douti[r4.w], 1);
}

// ------------- K6a: exclusive scan of in-degrees (1024 threads, int4) -------------
__global__ __launch_bounds__(1024)
void k6a_scan(const int* __restrict__ cnt, int* __restrict__ off) {
  __shared__ int s[1024];
  const int t = threadIdx.x;
  int4 v[5];
  int sum = 0;
  const int4* p4 = (const int4*)(cnt + t * 20);
#pragma unroll
  for (int i = 0; i < 5; ++i) {
    v[i] = p4[i];
    sum += v[i].x + v[i].y + v[i].z + v[i].w;
  }
  s[t] = sum;
  __syncthreads();
  for (int o = 1; o < 1024; o <<= 1) {
    const int add = (t >= o) ? s[t - o] : 0;
    __syncthreads();
    s[t] += add;
    __syncthreads();
  }
  int run = (t == 0) ? 0 : s[t - 1];
  if (t == 0) off[0] = 0;
  const int base = t * 20;
#pragma unroll
  for (int i = 0; i < 5; ++i) {
    const int vals[4] = {v[i].x, v[i].y, v[i].z, v[i].w};
#pragma unroll
    for (int j = 0; j < 4; ++j) {
      const int idx = base + i * 4 + j;
      if (idx < NN) { run += vals[j]; off[idx + 1] = run; }
    }
  }
}

// ------------- K6b: fill CSR (rows bucketed by col) -------------
__global__ __launch_bounds__(256)
void k6b_fill(const int* __restrict__ ei, const int* __restrict__ coff,
              int* __restrict__ cursor, int* __restrict__ crow) {
  const int e = blockIdx.x * 256 + threadIdx.x;
  const int r = ei[e], c = ei[EE + e];
  const int pos = atomicAdd(&cursor[c], 1);
  crow[coff[c] + pos] = r;
}

// ------------- K7: gather relational bias; one wave per node; zbuf += sig(b)*agg ----
__global__ __launch_bounds__(256)
void k7_gather(const int* __restrict__ coff, const int* __restrict__ crow,
               const int* __restrict__ douti, const _Float16* __restrict__ vh,
               const float* __restrict__ bp, float* __restrict__ zbuf) {
  const int node = blockIdx.x * 4 + (threadIdx.x >> 6);
  const int lane = threadIdx.x & 63;
  const int o0 = coff[node], o1 = coff[node + 1];
  float a0 = 0.f, a1 = 0.f, a2 = 0.f, a3 = 0.f;
  if (o1 > o0) {
    int e = o0;
    for (; e + 4 <= o1; e += 4) {
      const int r0 = crow[e], r1 = crow[e + 1], r2 = crow[e + 2], r3 = crow[e + 3];
      const float w0 = rsqrtf((float)douti[r0]);
      const float w1 = rsqrtf((float)douti[r1]);
      const float w2 = rsqrtf((float)douti[r2]);
      const float w3 = rsqrtf((float)douti[r3]);
      const f16x4 v0 = *(const f16x4*)(vh + (size_t)r0 * 256 + lane * 4);
      const f16x4 v1 = *(const f16x4*)(vh + (size_t)r1 * 256 + lane * 4);
      const f16x4 v2 = *(const f16x4*)(vh + (size_t)r2 * 256 + lane * 4);
      const f16x4 v3 = *(const f16x4*)(vh + (size_t)r3 * 256 + lane * 4);
      a0 += w0 * (float)v0[0] + w1 * (float)v1[0] + w2 * (float)v2[0] + w3 * (float)v3[0];
      a1 += w0 * (float)v0[1] + w1 * (float)v1[1] + w2 * (float)v2[1] + w3 * (float)v3[1];
      a2 += w0 * (float)v0[2] + w1 * (float)v1[2] + w2 * (float)v2[2] + w3 * (float)v3[2];
      a3 += w0 * (float)v0[3] + w1 * (float)v1[3] + w2 * (float)v2[3] + w3 * (float)v3[3];
    }
    for (; e < o1; ++e) {
      const int r = crow[e];
      const float wr = rsqrtf((float)douti[r]);
      const f16x4 vv = *(const f16x4*)(vh + (size_t)r * 256 + lane * 4);
      a0 += wr * (float)vv[0]; a1 += wr * (float)vv[1];
      a2 += wr * (float)vv[2]; a3 += wr * (float)vv[3];
    }
    const float rin = rsqrtf((float)(o1 - o0));
    a0 *= rin; a1 *= rin; a2 *= rin; a3 *= rin;
  }
  const float sg = 1.f / (1.f + expf(-bp[lane >> 4]));   // head = (lane*4)>>6
  float* dst = zbuf + (size_t)node * 256 + lane * 4;
  const float4 old = *(const float4*)dst;
  *(float4*)dst = make_float4(old.x + sg * a0, old.y + sg * a1,
                              old.z + sg * a2, old.w + sg * a3);
}

// ------------- K8: out = zbuf @ Wo^T + bo -------------
__global__ __launch_bounds__(256)
void k8_out(const float* __restrict__ zbuf, const float* __restrict__ Wo,
            const float* __restrict__ bo, float* __restrict__ out) {
  __shared__ float WoT[256 * 33];
  __shared__ float zbl[8 * 256];
  const int t = threadIdx.x;
  const int ch = blockIdx.y;  // 0/1 -> output cols [ch*32, ch*32+32)
#pragma unroll
  for (int l = 0; l < 32; ++l) {
    WoT[t * 33 + l] = Wo[(ch * 32 + l) * 256 + t];
  }
  const int nl = t >> 5, cp = t & 31;
  const float bias = bo[ch * 32 + cp];
  for (int g = blockIdx.x; g < 2500; g += gridDim.x) {
    __syncthreads();
#pragma unroll
    for (int l = 0; l < 2; ++l) {
      const int f4 = l * 256 + t;
      *(float4*)&zbl[f4 * 4] = *(const float4*)(zbuf + (size_t)g * 2048 + f4 * 4);
    }
    __syncthreads();
    float acc = bias;
#pragma unroll
    for (int i4 = 0; i4 < 64; ++i4) {
      const float4 z4 = *(const float4*)&zbl[nl * 256 + i4 * 4];
      acc = fmaf(z4.x, WoT[(i4 * 4 + 0) * 33 + cp], acc);
      acc = fmaf(z4.y, WoT[(i4 * 4 + 1) * 33 + cp], acc);
      acc = fmaf(z4.z, WoT[(i4 * 4 + 2) * 33 + cp], acc);
      acc = fmaf(z4.w, WoT[(i4 * 4 + 3) * 33 + cp], acc);
    }
    out[((size_t)g * 8 + nl) * 64 + ch * 32 + cp] = acc;
  }
}

extern "C" void kernel_launch(void* const* d_in, const int* in_sizes, int n_in,
                              void* d_out, int out_size, void* d_ws, size_t ws_size,
                              hipStream_t stream) {
  (void)in_sizes; (void)n_in; (void)out_size; (void)ws_size;
  const float* z    = (const float*)d_in[0];
  const float* feat = (const float*)d_in[1];
  const int*   ei   = (const int*)d_in[2];
  const float* tau  = (const float*)d_in[3];
  const float* Wq_w = (const float*)d_in[4];
  const float* Wq_b = (const float*)d_in[5];
  const float* Wk_w = (const float*)d_in[6];
  const float* Wk_b = (const float*)d_in[7];
  const float* Wv_w = (const float*)d_in[8];
  const float* Wv_b = (const float*)d_in[9];
  const float* Wo_w = (const float*)d_in[10];
  const float* Wo_b = (const float*)d_in[11];
  const float* bp   = (const float*)d_in[12];
  const float* proj = (const float*)d_in[13];
  float* out = (float*)d_out;

  char* p = (char*)d_ws;
  auto alloc = [&](size_t bytes) { char* r = p; p += (bytes + 255) & ~(size_t)255; return r; };
  _Float16* Wf    = (_Float16*)alloc((size_t)256 * 1024 * 2);
  float*    bbig  = (float*)alloc(1024 * 4);
  _Float16* vh    = (_Float16*)alloc((size_t)NN * 256 * 2);
  float*    qp    = (float*)alloc((size_t)NN * 120 * 4);
  float*    kbuf  = (float*)alloc((size_t)NN * 120 * 4);
  float*    zbuf  = (float*)alloc((size_t)NN * 256 * 4);
  float*    partial = (float*)alloc((size_t)4 * NCH * 1952 * 4);
  float*    kvs   = (float*)alloc(7680 * 4);
  float*    ksum  = (float*)alloc(120 * 4);
  // ---- contiguous zero-region ----
  char* z0 = p;
  unsigned* kmaxU = (unsigned*)alloc(16);
  int*      dini  = (int*)alloc((size_t)20480 * 4);   // padded for int4 scan
  int*      douti = (int*)alloc((size_t)NN * 4);
  int*      cursor= (int*)alloc((size_t)NN * 4);
  char* z1 = p;
  int*      coff  = (int*)alloc((size_t)(NN + 1) * 4);
  int*      crow  = (int*)alloc((size_t)EE * 4);

  hipMemsetAsync(z0, 0, (size_t)(z1 - z0), stream);

  k0_build<<<1024, 256, 0, stream>>>(Wq_w, Wk_w, Wv_w, Wq_b, Wk_b, Wv_b, proj, tau, Wf, bbig);
  k5_deg<<<(EE / 4 + 255) / 256, 256, 0, stream>>>(ei, dini, douti);
  k6a_scan<<<1, 1024, 0, stream>>>(dini, coff);
  k6b_fill<<<EE / 256, 256, 0, stream>>>(ei, coff, cursor, crow);
  k1_qk<<<NN / 16, 256, 0, stream>>>(feat, Wf, bbig, tau, qp, kbuf, kmaxU);
  k1_v<<<NN / 32, 256, 0, stream>>>(z, Wf, bbig, vh);
  k3_kvs<<<dim3(NCH, 4), 256, 0, stream>>>(kbuf, vh, kmaxU, partial);
  k3b_reduce<<<(4 * 1952 + 255) / 256, 256, 0, stream>>>(partial, kvs, ksum);
  k4_attn<<<NN / 32, 256, 0, stream>>>(qp, kvs, ksum, zbuf);
  k7_gather<<<NN / 4, 256, 0, stream>>>(coff, crow, douti, vh, bp, zbuf);
  k8_out<<<dim3(512, 2), 256, 0, stream>>>(zbuf, Wo_w, Wo_b, out);
}

// Round 6
// 310.418 us; speedup vs baseline: 1.5109x; 1.0257x over previous
//
#include <hip/hip_runtime.h>

#define NN 20000
#define EE 320000
#define RATIO_F 0.18257418583505536f   // 1/sqrt(30)
#define EPS_F 1e-6f
#define SCALE_D4 0.35355339059327373f  // 64^-0.25
#define NCH 157                        // ceil(20000/128) k3 chunks

typedef _Float16 f16x8 __attribute__((ext_vector_type(8)));
typedef _Float16 f16x4 __attribute__((ext_vector_type(4)));
typedef float f32x4 __attribute__((ext_vector_type(4)));

__device__ __forceinline__ unsigned fenc(float x) {
  unsigned u = __float_as_uint(x);
  return (u & 0x80000000u) ? ~u : (u | 0x80000000u);
}
__device__ __forceinline__ float fdec(unsigned u) {
  return (u & 0x80000000u) ? __uint_as_float(u & 0x7FFFFFFFu) : __uint_as_float(~u);
}
__device__ __forceinline__ void fma4(float* a, float s, float4 b) {
  a[0] = fmaf(s, b.x, a[0]);
  a[1] = fmaf(s, b.y, a[1]);
  a[2] = fmaf(s, b.z, a[2]);
  a[3] = fmaf(s, b.w, a[3]);
}

// =====================================================================
// K0: build fused weight plane (f16) in MFMA B-fragment order.
// Columns (1024 = 64 cts): [0,256)=q  [256,512)=k  [512,768)=v
//   xd_q head h = cts 48+2h,49+2h (m<30 valid); xd_k head h = cts 56+2h,57+2h
// Fragment fi = ct*8+kt (512 f16); lane l=(g*16+cl), elem j holds
// W[k=32*kt+8*g+j][col=ct*16+cl].
// =====================================================================
__global__ __launch_bounds__(256)
void k0_build(const float* __restrict__ Wq, const float* __restrict__ Wk,
              const float* __restrict__ Wv, const float* __restrict__ bq,
              const float* __restrict__ bk, const float* __restrict__ bv,
              const float* __restrict__ proj, const float* __restrict__ tau,
              _Float16* __restrict__ Wf, float* __restrict__ bbig) {
  const int col = blockIdx.x;
  const int i = threadIdx.x;   // k index
  const float s = rsqrtf(tau[0]) * SCALE_D4;
  float val = 0.f, bias = 0.f;
  if (col < 256) {
    val = Wq[col * 256 + i]; bias = bq[col];
  } else if (col < 512) {
    const int c = col - 256;
    val = Wk[c * 256 + i]; bias = bk[c];
  } else if (col < 768) {
    const int c = col - 512;
    val = Wv[c * 256 + i]; bias = bv[c];
  } else {
    const int rr = col - 768;
    const int grp = rr >> 7;             // 0 = q, 1 = k
    const int h = (rr >> 5) & 3, m = rr & 31;
    if (m < 30) {
      const float* W = grp ? Wk : Wq;
      const float* bb = grp ? bk : bq;
      float a = 0.f, ba = 0.f;
#pragma unroll 8
      for (int d = 0; d < 64; ++d) {
        const float pr = proj[m * 64 + d];
        a  = fmaf(pr, W[(h * 64 + d) * 256 + i], a);
        ba = fmaf(pr, bb[h * 64 + d], ba);
      }
      val = s * a; bias = s * ba;
    }
  }
  const int kt = i >> 5, gg = (i >> 3) & 3, j = i & 7;
  const int lane = gg * 16 + (col & 15);
  const size_t off = (size_t)((col >> 4) * 8 + kt) * 512 + lane * 8 + j;
  Wf[off] = (_Float16)val;
  if (i == 0) bbig[col] = bias;
}

// ---- A-fragment loader: 16 rows x 256 K of f32 -> f16 hi + f16 residual ----
__device__ __forceinline__ void load_frags16(const float* __restrict__ p, int g,
                                             f16x8* Ah, f16x8* Al) {
#pragma unroll
  for (int kt = 0; kt < 8; ++kt) {
    const float4 f0 = *(const float4*)(p + kt * 32 + g * 8);
    const float4 f1 = *(const float4*)(p + kt * 32 + g * 8 + 4);
    float ff[8] = {f0.x, f0.y, f0.z, f0.w, f1.x, f1.y, f1.z, f1.w};
    union { _Float16 h[8]; f16x8 v; } hu, lu;
#pragma unroll
    for (int j = 0; j < 8; ++j) {
      const _Float16 hb = (_Float16)ff[j];
      hu.h[j] = hb;
      lu.h[j] = (_Float16)(ff[j] - (float)hb);
    }
    Ah[kt] = hu.v; Al[kt] = lu.v;
  }
}

// ---- one 16x16 C-tile over K=256, B from LDS slot (conflict-free b128) ----
__device__ __forceinline__ f32x4 ct_lds(const _Float16* __restrict__ blds,
                                        int slot, int lane, float bb,
                                        const f16x8* Ah, const f16x8* Al) {
  const _Float16* bp = blds + slot * 4096 + lane * 8;
  f16x8 bfr[8];
#pragma unroll
  for (int kt = 0; kt < 8; ++kt)
    bfr[kt] = *(const f16x8*)(bp + kt * 512);
  f32x4 a0 = {0.f, 0.f, 0.f, 0.f}, a1 = {0.f, 0.f, 0.f, 0.f};
#pragma unroll
  for (int kt = 0; kt < 8; ++kt) {
    a0 = __builtin_amdgcn_mfma_f32_16x16x32_f16(Ah[kt], bfr[kt], a0, 0, 0, 0);
    a1 = __builtin_amdgcn_mfma_f32_16x16x32_f16(Al[kt], bfr[kt], a1, 0, 0, 0);
  }
  f32x4 r;
#pragma unroll
  for (int j = 0; j < 4; ++j) r[j] = a0[j] + a1[j] + bb;
  return r;
}

// =====================================================================
// K1a: q/k/xd for one head per block (blockIdx.y), 8 waves x 16 rows.
// B for the head's 12 cts one-shot staged in LDS (96 KB), ONE barrier.
// All reductions wave-local (shfl), no further sync.
// LDS slots: 0-3 q cts, 4-7 k cts, 8-9 xd_q, 10-11 xd_k.
// =====================================================================
__global__ __launch_bounds__(512, 1)
void k1_qk(const float* __restrict__ feat, const _Float16* __restrict__ Wf,
           const float* __restrict__ bbig, const float* __restrict__ tau,
           float* __restrict__ qp, float* __restrict__ kbuf,
           unsigned* __restrict__ kmaxU) {
  __shared__ __align__(16) _Float16 blds[12 * 4096];   // 96 KB
  const int t = threadIdx.x;
  const int wid = t >> 6, lane = t & 63;
  const int g = lane >> 4, cl = lane & 15;
  const int h = blockIdx.y;
  const int rbase = blockIdx.x * 128 + wid * 16;
  const float sc = rsqrtf(tau[0]) * SCALE_D4;
  const float h2 = 0.5f * sc * sc;

  // ---- stage 12 cts (96 KB), coalesced ----
#pragma unroll
  for (int s = 0; s < 12; ++s) {
    const int ct = (s < 4) ? (h * 4 + s)
                 : (s < 8) ? (16 + h * 4 + (s - 4))
                 : (s < 10) ? (48 + 2 * h + (s - 8))
                            : (56 + 2 * h + (s - 10));
    *(uint4*)&blds[(s * 512 + t) * 8] = *(const uint4*)(Wf + (size_t)ct * 4096 + t * 8);
  }
  // ---- A fragments (overlap with staging drain) ----
  int arow = rbase + cl; if (arow > NN - 1) arow = NN - 1;
  f16x8 Ah[8], Al[8];
  load_frags16(feat + (size_t)arow * 256, g, Ah, Al);
  __syncthreads();

  float bias_cache[12];
#pragma unroll
  for (int s = 0; s < 12; ++s) {
    const int ct = (s < 4) ? (h * 4 + s)
                 : (s < 8) ? (16 + h * 4 + (s - 4))
                 : (s < 10) ? (48 + 2 * h + (s - 8))
                            : (56 + 2 * h + (s - 10));
    bias_cache[s] = bbig[ct * 16 + cl];
  }

  // ---- q/k diag ----
  float dsq[4] = {0.f, 0.f, 0.f, 0.f}, dsk[4] = {0.f, 0.f, 0.f, 0.f};
#pragma unroll
  for (int c4 = 0; c4 < 4; ++c4) {
    const f32x4 a = ct_lds(blds, c4, lane, bias_cache[c4], Ah, Al);
#pragma unroll
    for (int j = 0; j < 4; ++j) dsq[j] = fmaf(a[j], a[j], dsq[j]);
  }
#pragma unroll
  for (int c4 = 0; c4 < 4; ++c4) {
    const f32x4 a = ct_lds(blds, 4 + c4, lane, bias_cache[4 + c4], Ah, Al);
#pragma unroll
    for (int j = 0; j < 4; ++j) dsk[j] = fmaf(a[j], a[j], dsk[j]);
  }
#pragma unroll
  for (int m = 1; m < 16; m <<= 1) {
#pragma unroll
    for (int j = 0; j < 4; ++j) {
      dsq[j] += __shfl_xor(dsq[j], m);
      dsk[j] += __shfl_xor(dsk[j], m);
    }
  }
  {  // ---- xd_q -> qp ----
    const f32x4 x0 = ct_lds(blds, 8, lane, bias_cache[8], Ah, Al);
    const f32x4 x1 = ct_lds(blds, 9, lane, bias_cache[9], Ah, Al);
#pragma unroll
    for (int j = 0; j < 4; ++j) {
      float mv = fmaxf(x0[j], (cl < 14) ? x1[j] : -3.4e38f);
#pragma unroll
      for (int m = 1; m < 16; m <<= 1) mv = fmaxf(mv, __shfl_xor(mv, m));
      const float dg = h2 * dsq[j];
      const int r = rbase + 4 * g + j;
      if (r < NN) {
        float* dst = qp + (size_t)r * 120 + h * 30;
        dst[cl] = RATIO_F * (expf(x0[j] - dg - mv) + EPS_F);
        if (cl < 14) dst[16 + cl] = RATIO_F * (expf(x1[j] - dg - mv) + EPS_F);
      }
    }
  }
  {  // ---- xd_k -> kbuf + global head max ----
    const f32x4 x0 = ct_lds(blds, 10, lane, bias_cache[10], Ah, Al);
    const f32x4 x1 = ct_lds(blds, 11, lane, bias_cache[11], Ah, Al);
    float wmax = -3.4e38f;
#pragma unroll
    for (int j = 0; j < 4; ++j) {
      float mv = fmaxf(x0[j], (cl < 14) ? x1[j] : -3.4e38f);
#pragma unroll
      for (int m = 1; m < 16; m <<= 1) mv = fmaxf(mv, __shfl_xor(mv, m));
      wmax = fmaxf(wmax, mv);
      const float dg = h2 * dsk[j];
      const int r = rbase + 4 * g + j;
      if (r < NN) {
        float* dst = kbuf + (size_t)r * 120 + h * 30;
        dst[cl] = x0[j] - dg;
        if (cl < 14) dst[16 + cl] = x1[j] - dg;
      }
    }
    wmax = fmaxf(wmax, __shfl_xor(wmax, 16));
    wmax = fmaxf(wmax, __shfl_xor(wmax, 32));
    if (lane == 0) atomicMax(&kmaxU[h], fenc(wmax));
  }
}

// =====================================================================
// K1b: v = z @ Wv (+bias) -> f16. Block = col-half (blockIdx.y), 8 waves
// x 16 rows; 8 cts one-shot staged (64 KB), one barrier.
// =====================================================================
__global__ __launch_bounds__(512, 1)
void k1_v(const float* __restrict__ zin, const _Float16* __restrict__ Wf,
          const float* __restrict__ bbig, _Float16* __restrict__ vh) {
  __shared__ __align__(16) _Float16 blds[8 * 4096];    // 64 KB
  const int t = threadIdx.x;
  const int wid = t >> 6, lane = t & 63;
  const int g = lane >> 4, cl = lane & 15;
  const int half = blockIdx.y;
  const int ct0 = 32 + half * 8;
  const int rbase = blockIdx.x * 128 + wid * 16;
#pragma unroll
  for (int s = 0; s < 8; ++s)
    *(uint4*)&blds[(s * 512 + t) * 8] = *(const uint4*)(Wf + (size_t)(ct0 + s) * 4096 + t * 8);
  int arow = rbase + cl; if (arow > NN - 1) arow = NN - 1;
  f16x8 Ah[8], Al[8];
  load_frags16(zin + (size_t)arow * 256, g, Ah, Al);
  __syncthreads();
#pragma unroll
  for (int c = 0; c < 8; ++c) {
    const f32x4 a = ct_lds(blds, c, lane, bbig[(ct0 + c) * 16 + cl], Ah, Al);
    const int colb = (half * 8 + c) * 16 + cl;
#pragma unroll
    for (int j = 0; j < 4; ++j) {
      const int r = rbase + 4 * g + j;
      if (r < NN) vh[(size_t)r * 256 + colb] = (_Float16)a[j];
    }
  }
}

// ------------- K3a: per-chunk partials of kvs/ksum (no atomics) -------------
__global__ __launch_bounds__(256)
void k3_kvs(const float* __restrict__ kbr, const _Float16* __restrict__ vh,
            const unsigned* __restrict__ kmaxU, float* __restrict__ partial) {
  __shared__ float kpch[128 * 32];
  __shared__ float vch[128 * 68];
  const int h = blockIdx.y;
  const int n0 = blockIdx.x * 128;
  const int cnt = min(128, NN - n0);
  const int t = threadIdx.x;
  const float mx = fdec(kmaxU[h]);
  const int m = t >> 3, dg = t & 7, d0 = dg * 8;
#pragma unroll
  for (int l = 0; l < 15; ++l) {
    const int flat = l * 256 + t;
    const int nl = flat / 30, mm = flat - nl * 30;
    kpch[nl * 32 + mm] = (nl < cnt)
        ? RATIO_F * (expf(kbr[(size_t)(n0 + nl) * 120 + h * 30 + mm] - mx) + EPS_F)
        : 0.f;
  }
#pragma unroll
  for (int l = 0; l < 8; ++l) {
    const int f4 = l * 256 + t;
    const int nl = f4 >> 4, dd = (f4 & 15) * 4;
    float4 vv = make_float4(0.f, 0.f, 0.f, 0.f);
    if (nl < cnt) {
      f16x4 u = *(const f16x4*)(vh + (size_t)(n0 + nl) * 256 + h * 64 + dd);
      vv = make_float4((float)u[0], (float)u[1], (float)u[2], (float)u[3]);
    }
    *(float4*)&vch[nl * 68 + dd] = vv;
  }
  __syncthreads();
  float acc[8] = {0, 0, 0, 0, 0, 0, 0, 0};
  float asum = 0.f;
  const int ms = (m < 30) ? m : 0;
  for (int nl = 0; nl < cnt; ++nl) {
    const float kv = kpch[nl * 32 + ms];
    const float4 va = *(const float4*)&vch[nl * 68 + d0];
    const float4 vb = *(const float4*)&vch[nl * 68 + d0 + 4];
    fma4(&acc[0], kv, va);
    fma4(&acc[4], kv, vb);
    asum += kv;
  }
  if (m < 30) {
    float* dst = partial + ((size_t)blockIdx.y * NCH + blockIdx.x) * 1952 + m * 64 + d0;
#pragma unroll
    for (int j = 0; j < 8; ++j) dst[j] = acc[j];
    if (dg == 0)
      partial[((size_t)blockIdx.y * NCH + blockIdx.x) * 1952 + 1920 + m] = asum;
  }
}

// ------------- K3b: reduce partials -> kvs, ksum -------------
__global__ __launch_bounds__(256)
void k3b_reduce(const float* __restrict__ partial, float* __restrict__ kvs,
                float* __restrict__ ksum) {
  const int idx = blockIdx.x * 256 + threadIdx.x;
  if (idx >= 4 * 1952) return;
  const int h = idx / 1952, q = idx - h * 1952;
  float s = 0.f;
  for (int c = 0; c < NCH; ++c)
    s += partial[((size_t)h * NCH + c) * 1952 + q];
  if (q < 1920) kvs[h * 1920 + q] = s;
  else if (q < 1950) ksum[h * 30 + (q - 1920)] = s;
}

// ------------- K4: num/den -> zbuf -------------
__global__ __launch_bounds__(256)
void k4_attn(const float* __restrict__ qp, const float* __restrict__ kvs,
             const float* __restrict__ ksum, float* __restrict__ zbuf) {
  __shared__ float kvsl[120 * 68];
  __shared__ float ksl[120];
  __shared__ float qpl[32 * 120];
  const int t = threadIdx.x;
  const int n0 = blockIdx.x * 32;
#pragma unroll
  for (int l = 0; l < 30; ++l) {
    const int f = l * 256 + t;           // 7680
    const int hm = f >> 6, d = f & 63;
    kvsl[hm * 68 + d] = kvs[f];
  }
  if (t < 120) ksl[t] = ksum[t];
#pragma unroll
  for (int l = 0; l < 15; ++l) {
    const int f = l * 256 + t;           // 3840
    qpl[f] = qp[(size_t)n0 * 120 + f];
  }
  __syncthreads();
  const int nl = t >> 3, dg = t & 7, d0 = dg * 8;
  const float* qrow = &qpl[nl * 120];
  float den[4] = {0, 0, 0, 0};
  for (int m = 0; m < 30; ++m) {
#pragma unroll
    for (int hh = 0; hh < 4; ++hh) den[hh] = fmaf(qrow[hh * 30 + m], ksl[hh * 30 + m], den[hh]);
  }
  float acc[4][8] = {};
  for (int m = 0; m < 30; ++m) {
#pragma unroll
    for (int hh = 0; hh < 4; ++hh) {
      const float qv = qrow[hh * 30 + m];
      const float* kr = &kvsl[(hh * 30 + m) * 68 + d0];
      const float4 ka = *(const float4*)kr;
      const float4 kb = *(const float4*)(kr + 4);
      fma4(&acc[hh][0], qv, ka);
      fma4(&acc[hh][4], qv, kb);
    }
  }
  const size_t n = n0 + nl;
#pragma unroll
  for (int hh = 0; hh < 4; ++hh) {
    const float inv = 1.0f / den[hh];
    float4 o1 = make_float4(acc[hh][0] * inv, acc[hh][1] * inv, acc[hh][2] * inv, acc[hh][3] * inv);
    float4 o2 = make_float4(acc[hh][4] * inv, acc[hh][5] * inv, acc[hh][6] * inv, acc[hh][7] * inv);
    *(float4*)(zbuf + n * 256 + hh * 64 + d0) = o1;
    *(float4*)(zbuf + n * 256 + hh * 64 + d0 + 4) = o2;
  }
}

// ------------- K5: degree counts (int4 vectorized) -------------
__global__ __launch_bounds__(256)
void k5_deg(const int* __restrict__ ei, int* __restrict__ dini, int* __restrict__ douti) {
  const int q = blockIdx.x * 256 + threadIdx.x;
  if (q >= EE / 4) return;
  const int4 r4 = *(const int4*)(ei + q * 4);
  const int4 c4 = *(const int4*)(ei + EE + q * 4);
  atomicAdd(&dini[c4.x], 1); atomicAdd(&dini[c4.y], 1);
  atomicAdd(&dini[c4.z], 1); atomicAdd(&dini[c4.w], 1);
  atomicAdd(&douti[r4.x], 1); atomicAdd(&douti[r4.y], 1);
  atomicAdd(&douti[r4.z], 1); atomicAdd(&douti[r4.w], 1);
}

// ------------- K6a: exclusive scan of in-degrees (1024 threads, int4) -------------
__global__ __launch_bounds__(1024)
void k6a_scan(const int* __restrict__ cnt, int* __restrict__ off) {
  __shared__ int s[1024];
  const int t = threadIdx.x;
  int4 v[5];
  int sum = 0;
  const int4* p4 = (const int4*)(cnt + t * 20);
#pragma unroll
  for (int i = 0; i < 5; ++i) {
    v[i] = p4[i];
    sum += v[i].x + v[i].y + v[i].z + v[i].w;
  }
  s[t] = sum;
  __syncthreads();
  for (int o = 1; o < 1024; o <<= 1) {
    const int add = (t >= o) ? s[t - o] : 0;
    __syncthreads();
    s[t] += add;
    __syncthreads();
  }
  int run = (t == 0) ? 0 : s[t - 1];
  if (t == 0) off[0] = 0;
  const int base = t * 20;
#pragma unroll
  for (int i = 0; i < 5; ++i) {
    const int vals[4] = {v[i].x, v[i].y, v[i].z, v[i].w};
#pragma unroll
    for (int j = 0; j < 4; ++j) {
      const int idx = base + i * 4 + j;
      if (idx < NN) { run += vals[j]; off[idx + 1] = run; }
    }
  }
}

// ------------- K6b: fill CSR (rows bucketed by col) -------------
__global__ __launch_bounds__(256)
void k6b_fill(const int* __restrict__ ei, const int* __restrict__ coff,
              int* __restrict__ cursor, int* __restrict__ crow) {
  const int e = blockIdx.x * 256 + threadIdx.x;
  const int r = ei[e], c = ei[EE + e];
  const int pos = atomicAdd(&cursor[c], 1);
  crow[coff[c] + pos] = r;
}

// ------------- K7: gather relational bias; one wave per node; zbuf += sig(b)*agg ----
__global__ __launch_bounds__(256)
void k7_gather(const int* __restrict__ coff, const int* __restrict__ crow,
               const int* __restrict__ douti, const _Float16* __restrict__ vh,
               const float* __restrict__ bp, float* __restrict__ zbuf) {
  const int node = blockIdx.x * 4 + (threadIdx.x >> 6);
  const int lane = threadIdx.x & 63;
  const int o0 = coff[node], o1 = coff[node + 1];
  float a0 = 0.f, a1 = 0.f, a2 = 0.f, a3 = 0.f;
  if (o1 > o0) {
    int e = o0;
    for (; e + 4 <= o1; e += 4) {
      const int r0 = crow[e], r1 = crow[e + 1], r2 = crow[e + 2], r3 = crow[e + 3];
      const float w0 = rsqrtf((float)douti[r0]);
      const float w1 = rsqrtf((float)douti[r1]);
      const float w2 = rsqrtf((float)douti[r2]);
      const float w3 = rsqrtf((float)douti[r3]);
      const f16x4 v0 = *(const f16x4*)(vh + (size_t)r0 * 256 + lane * 4);
      const f16x4 v1 = *(const f16x4*)(vh + (size_t)r1 * 256 + lane * 4);
      const f16x4 v2 = *(const f16x4*)(vh + (size_t)r2 * 256 + lane * 4);
      const f16x4 v3 = *(const f16x4*)(vh + (size_t)r3 * 256 + lane * 4);
      a0 += w0 * (float)v0[0] + w1 * (float)v1[0] + w2 * (float)v2[0] + w3 * (float)v3[0];
      a1 += w0 * (float)v0[1] + w1 * (float)v1[1] + w2 * (float)v2[1] + w3 * (float)v3[1];
      a2 += w0 * (float)v0[2] + w1 * (float)v1[2] + w2 * (float)v2[2] + w3 * (float)v3[2];
      a3 += w0 * (float)v0[3] + w1 * (float)v1[3] + w2 * (float)v2[3] + w3 * (float)v3[3];
    }
    for (; e < o1; ++e) {
      const int r = crow[e];
      const float wr = rsqrtf((float)douti[r]);
      const f16x4 vv = *(const f16x4*)(vh + (size_t)r * 256 + lane * 4);
      a0 += wr * (float)vv[0]; a1 += wr * (float)vv[1];
      a2 += wr * (float)vv[2]; a3 += wr * (float)vv[3];
    }
    const float rin = rsqrtf((float)(o1 - o0));
    a0 *= rin; a1 *= rin; a2 *= rin; a3 *= rin;
  }
  const float sg = 1.f / (1.f + expf(-bp[lane >> 4]));   // head = (lane*4)>>6
  float* dst = zbuf + (size_t)node * 256 + lane * 4;
  const float4 old = *(const float4*)dst;
  *(float4*)dst = make_float4(old.x + sg * a0, old.y + sg * a1,
                              old.z + sg * a2, old.w + sg * a3);
}

// ------------- K8: out = zbuf @ Wo^T + bo -------------
__global__ __launch_bounds__(256)
void k8_out(const float* __restrict__ zbuf, const float* __restrict__ Wo,
            const float* __restrict__ bo, float* __restrict__ out) {
  __shared__ float WoT[256 * 33];
  __shared__ float zbl[8 * 256];
  const int t = threadIdx.x;
  const int ch = blockIdx.y;  // 0/1 -> output cols [ch*32, ch*32+32)
#pragma unroll
  for (int l = 0; l < 32; ++l) {
    WoT[t * 33 + l] = Wo[(ch * 32 + l) * 256 + t];
  }
  const int nl = t >> 5, cp = t & 31;
  const float bias = bo[ch * 32 + cp];
  for (int g = blockIdx.x; g < 2500; g += gridDim.x) {
    __syncthreads();
#pragma unroll
    for (int l = 0; l < 2; ++l) {
      const int f4 = l * 256 + t;
      *(float4*)&zbl[f4 * 4] = *(const float4*)(zbuf + (size_t)g * 2048 + f4 * 4);
    }
    __syncthreads();
    float acc = bias;
#pragma unroll
    for (int i4 = 0; i4 < 64; ++i4) {
      const float4 z4 = *(const float4*)&zbl[nl * 256 + i4 * 4];
      acc = fmaf(z4.x, WoT[(i4 * 4 + 0) * 33 + cp], acc);
      acc = fmaf(z4.y, WoT[(i4 * 4 + 1) * 33 + cp], acc);
      acc = fmaf(z4.z, WoT[(i4 * 4 + 2) * 33 + cp], acc);
      acc = fmaf(z4.w, WoT[(i4 * 4 + 3) * 33 + cp], acc);
    }
    out[((size_t)g * 8 + nl) * 64 + ch * 32 + cp] = acc;
  }
}

extern "C" void kernel_launch(void* const* d_in, const int* in_sizes, int n_in,
                              void* d_out, int out_size, void* d_ws, size_t ws_size,
                              hipStream_t stream) {
  (void)in_sizes; (void)n_in; (void)out_size; (void)ws_size;
  const float* z    = (const float*)d_in[0];
  const float* feat = (const float*)d_in[1];
  const int*   ei   = (const int*)d_in[2];
  const float* tau  = (const float*)d_in[3];
  const float* Wq_w = (const float*)d_in[4];
  const float* Wq_b = (const float*)d_in[5];
  const float* Wk_w = (const float*)d_in[6];
  const float* Wk_b = (const float*)d_in[7];
  const float* Wv_w = (const float*)d_in[8];
  const float* Wv_b = (const float*)d_in[9];
  const float* Wo_w = (const float*)d_in[10];
  const float* Wo_b = (const float*)d_in[11];
  const float* bp   = (const float*)d_in[12];
  const float* proj = (const float*)d_in[13];
  float* out = (float*)d_out;

  char* p = (char*)d_ws;
  auto alloc = [&](size_t bytes) { char* r = p; p += (bytes + 255) & ~(size_t)255; return r; };
  _Float16* Wf    = (_Float16*)alloc((size_t)256 * 1024 * 2);
  float*    bbig  = (float*)alloc(1024 * 4);
  _Float16* vh    = (_Float16*)alloc((size_t)NN * 256 * 2);
  float*    qp    = (float*)alloc((size_t)NN * 120 * 4);
  float*    kbuf  = (float*)alloc((size_t)NN * 120 * 4);
  float*    zbuf  = (float*)alloc((size_t)NN * 256 * 4);
  float*    partial = (float*)alloc((size_t)4 * NCH * 1952 * 4);
  float*    kvs   = (float*)alloc(7680 * 4);
  float*    ksum  = (float*)alloc(120 * 4);
  // ---- contiguous zero-region ----
  char* z0 = p;
  unsigned* kmaxU = (unsigned*)alloc(16);
  int*      dini  = (int*)alloc((size_t)20480 * 4);   // padded for int4 scan
  int*      douti = (int*)alloc((size_t)NN * 4);
  int*      cursor= (int*)alloc((size_t)NN * 4);
  char* z1 = p;
  int*      coff  = (int*)alloc((size_t)(NN + 1) * 4);
  int*      crow  = (int*)alloc((size_t)EE * 4);

  hipMemsetAsync(z0, 0, (size_t)(z1 - z0), stream);

  k0_build<<<1024, 256, 0, stream>>>(Wq_w, Wk_w, Wv_w, Wq_b, Wk_b, Wv_b, proj, tau, Wf, bbig);
  k5_deg<<<(EE / 4 + 255) / 256, 256, 0, stream>>>(ei, dini, douti);
  k6a_scan<<<1, 1024, 0, stream>>>(dini, coff);
  k6b_fill<<<EE / 256, 256, 0, stream>>>(ei, coff, cursor, crow);
  k1_qk<<<dim3(157, 4), 512, 0, stream>>>(feat, Wf, bbig, tau, qp, kbuf, kmaxU);
  k1_v<<<dim3(157, 2), 512, 0, stream>>>(z, Wf, bbig, vh);
  k3_kvs<<<dim3(NCH, 4), 256, 0, stream>>>(kbuf, vh, kmaxU, partial);
  k3b_reduce<<<(4 * 1952 + 255) / 256, 256, 0, stream>>>(partial, kvs, ksum);
  k4_attn<<<NN / 32, 256, 0, stream>>>(qp, kvs, ksum, zbuf);
  k7_gather<<<NN / 4, 256, 0, stream>>>(coff, crow, douti, vh, bp, zbuf);
  k8_out<<<dim3(512, 2), 256, 0, stream>>>(zbuf, Wo_w, Wo_b, out);
}

// Round 7
// 307.643 us; speedup vs baseline: 1.5245x; 1.0090x over previous
//
#include <hip/hip_runtime.h>

#define NN 20000
#define EE 320000
#define RATIO_F 0.18257418583505536f   // 1/sqrt(30)
#define EPS_F 1e-6f
#define SCALE_D4 0.35355339059327373f  // 64^-0.25
#define NCH 157                        // ceil(20000/128) k3 chunks

typedef _Float16 f16x8 __attribute__((ext_vector_type(8)));
typedef _Float16 f16x4 __attribute__((ext_vector_type(4)));
typedef float f32x4 __attribute__((ext_vector_type(4)));

__device__ __forceinline__ unsigned fenc(float x) {
  unsigned u = __float_as_uint(x);
  return (u & 0x80000000u) ? ~u : (u | 0x80000000u);
}
__device__ __forceinline__ float fdec(unsigned u) {
  return (u & 0x80000000u) ? __uint_as_float(u & 0x7FFFFFFFu) : __uint_as_float(~u);
}
__device__ __forceinline__ void fma4(float* a, float s, float4 b) {
  a[0] = fmaf(s, b.x, a[0]);
  a[1] = fmaf(s, b.y, a[1]);
  a[2] = fmaf(s, b.z, a[2]);
  a[3] = fmaf(s, b.w, a[3]);
}
// async global->LDS, 16B per lane; LDS dest must be wave-uniform base + lane*16
__device__ __forceinline__ void gload16(const void* g, void* l) {
  __builtin_amdgcn_global_load_lds(
      (const __attribute__((address_space(1))) unsigned int*)g,
      (__attribute__((address_space(3))) unsigned int*)l, 16, 0, 0);
}

// =====================================================================
// K0: build fused weight plane (f16) in MFMA B-fragment order.
// Columns (1024 = 64 cts): [0,256)=q  [256,512)=k  [512,768)=v
//   xd_q head h = cts 48+2h,49+2h (m<30 valid); xd_k head h = cts 56+2h,57+2h
// Fragment fi = ct*8+kt (512 f16); lane l=(g*16+cl), elem j holds
// W[k=32*kt+8*g+j][col=ct*16+cl].
// =====================================================================
__global__ __launch_bounds__(256)
void k0_build(const float* __restrict__ Wq, const float* __restrict__ Wk,
              const float* __restrict__ Wv, const float* __restrict__ bq,
              const float* __restrict__ bk, const float* __restrict__ bv,
              const float* __restrict__ proj, const float* __restrict__ tau,
              _Float16* __restrict__ Wf, float* __restrict__ bbig) {
  const int col = blockIdx.x;
  const int i = threadIdx.x;   // k index
  const float s = rsqrtf(tau[0]) * SCALE_D4;
  float val = 0.f, bias = 0.f;
  if (col < 256) {
    val = Wq[col * 256 + i]; bias = bq[col];
  } else if (col < 512) {
    const int c = col - 256;
    val = Wk[c * 256 + i]; bias = bk[c];
  } else if (col < 768) {
    const int c = col - 512;
    val = Wv[c * 256 + i]; bias = bv[c];
  } else {
    const int rr = col - 768;
    const int grp = rr >> 7;             // 0 = q, 1 = k
    const int h = (rr >> 5) & 3, m = rr & 31;
    if (m < 30) {
      const float* W = grp ? Wk : Wq;
      const float* bb = grp ? bk : bq;
      float a = 0.f, ba = 0.f;
#pragma unroll 8
      for (int d = 0; d < 64; ++d) {
        const float pr = proj[m * 64 + d];
        a  = fmaf(pr, W[(h * 64 + d) * 256 + i], a);
        ba = fmaf(pr, bb[h * 64 + d], ba);
      }
      val = s * a; bias = s * ba;
    }
  }
  const int kt = i >> 5, gg = (i >> 3) & 3, j = i & 7;
  const int lane = gg * 16 + (col & 15);
  const size_t off = (size_t)((col >> 4) * 8 + kt) * 512 + lane * 8 + j;
  Wf[off] = (_Float16)val;
  if (i == 0) bbig[col] = bias;
}

// ---- A-fragment loader: 16 rows x 256 K of f32 -> f16 hi + f16 residual.
// Loads grouped 8-at-a-time so 8 stay in flight before converts. ----
__device__ __forceinline__ void load_frags16(const float* __restrict__ p, int g,
                                             f16x8* Ah, f16x8* Al) {
#pragma unroll
  for (int hv = 0; hv < 2; ++hv) {
    float4 fr[8];
#pragma unroll
    for (int kt = 0; kt < 4; ++kt) {
      fr[kt * 2]     = *(const float4*)(p + (hv * 4 + kt) * 32 + g * 8);
      fr[kt * 2 + 1] = *(const float4*)(p + (hv * 4 + kt) * 32 + g * 8 + 4);
    }
#pragma unroll
    for (int kt = 0; kt < 4; ++kt) {
      const float ff[8] = {fr[kt*2].x, fr[kt*2].y, fr[kt*2].z, fr[kt*2].w,
                           fr[kt*2+1].x, fr[kt*2+1].y, fr[kt*2+1].z, fr[kt*2+1].w};
      union { _Float16 h[8]; f16x8 v; } hu, lu;
#pragma unroll
      for (int j = 0; j < 8; ++j) {
        const _Float16 hb = (_Float16)ff[j];
        hu.h[j] = hb;
        lu.h[j] = (_Float16)(ff[j] - (float)hb);
      }
      Ah[hv * 4 + kt] = hu.v; Al[hv * 4 + kt] = lu.v;
    }
  }
}

// ---- one 16x16 C-tile over K=256, B from LDS slot (conflict-free b128) ----
__device__ __forceinline__ f32x4 ct_lds(const _Float16* __restrict__ blds,
                                        int slot, int lane, float bb,
                                        const f16x8* Ah, const f16x8* Al) {
  const _Float16* bp = blds + slot * 4096 + lane * 8;
  f16x8 bfr[8];
#pragma unroll
  for (int kt = 0; kt < 8; ++kt)
    bfr[kt] = *(const f16x8*)(bp + kt * 512);
  f32x4 a0 = {0.f, 0.f, 0.f, 0.f}, a1 = {0.f, 0.f, 0.f, 0.f};
#pragma unroll
  for (int kt = 0; kt < 8; ++kt) {
    a0 = __builtin_amdgcn_mfma_f32_16x16x32_f16(Ah[kt], bfr[kt], a0, 0, 0, 0);
    a1 = __builtin_amdgcn_mfma_f32_16x16x32_f16(Al[kt], bfr[kt], a1, 0, 0, 0);
  }
  f32x4 r;
#pragma unroll
  for (int j = 0; j < 4; ++j) r[j] = a0[j] + a1[j] + bb;
  return r;
}

// =====================================================================
// K1: merged q/k/xd/v GEMM. grid (157, 6) x 512 thr (8 waves x 16 rows).
//  y<4: head y. Stage q+k cts (64 KB) via global_load_lds -> diag ->
//       restage 4 xd cts (32 KB) -> softmax-kernel epilogues.
//  y=4,5: v col-half. Stage 8 v cts -> store f16.
// LDS 64 KB -> 2 blocks/CU; launch_bounds(512,4) -> VGPR<=128 ->
// 16 waves/CU for latency hiding. All reductions wave-local.
// =====================================================================
__global__ __launch_bounds__(512, 4)
void k1_all(const float* __restrict__ feat, const float* __restrict__ zin,
            const _Float16* __restrict__ Wf, const float* __restrict__ bbig,
            const float* __restrict__ tau,
            float* __restrict__ qp, float* __restrict__ kbuf,
            _Float16* __restrict__ vh, unsigned* __restrict__ kmaxU) {
  __shared__ __align__(16) _Float16 blds[8 * 4096];   // 64 KB
  const int t = threadIdx.x;
  const int wid = t >> 6, lane = t & 63;
  const int g = lane >> 4, cl = lane & 15;
  const int y = blockIdx.y;
  const int rbase = blockIdx.x * 128 + wid * 16;
  int arow = rbase + cl; if (arow > NN - 1) arow = NN - 1;

  f16x8 Ah[8], Al[8];

  if (y < 4) {
    const int h = y;
    // ---- stage q cts (slots 0-3) + k cts (slots 4-7), async ----
#pragma unroll
    for (int s = 0; s < 8; ++s) {
      const int ct = (s < 4) ? (h * 4 + s) : (16 + h * 4 + (s - 4));
      gload16(Wf + (size_t)ct * 4096 + t * 8, &blds[(s * 512 + t) * 8]);
    }
    load_frags16(feat + (size_t)arow * 256, g, Ah, Al);
    __syncthreads();

    const float sc = rsqrtf(tau[0]) * SCALE_D4;
    const float h2 = 0.5f * sc * sc;

    // ---- q/k diag ----
    float dsq[4] = {0.f, 0.f, 0.f, 0.f}, dsk[4] = {0.f, 0.f, 0.f, 0.f};
#pragma unroll
    for (int c4 = 0; c4 < 4; ++c4) {
      const f32x4 a = ct_lds(blds, c4, lane, bbig[(h * 4 + c4) * 16 + cl], Ah, Al);
#pragma unroll
      for (int j = 0; j < 4; ++j) dsq[j] = fmaf(a[j], a[j], dsq[j]);
    }
#pragma unroll
    for (int c4 = 0; c4 < 4; ++c4) {
      const f32x4 a = ct_lds(blds, 4 + c4, lane, bbig[(16 + h * 4 + c4) * 16 + cl], Ah, Al);
#pragma unroll
      for (int j = 0; j < 4; ++j) dsk[j] = fmaf(a[j], a[j], dsk[j]);
    }
#pragma unroll
    for (int m = 1; m < 16; m <<= 1) {
#pragma unroll
      for (int j = 0; j < 4; ++j) {
        dsq[j] += __shfl_xor(dsq[j], m);
        dsk[j] += __shfl_xor(dsk[j], m);
      }
    }
    __syncthreads();   // all waves done reading slots 0-3
    // ---- restage xd cts into slots 0-3: 0,1=xd_q  2,3=xd_k ----
#pragma unroll
    for (int s = 0; s < 4; ++s) {
      const int ct = (s < 2) ? (48 + 2 * h + s) : (56 + 2 * h + (s - 2));
      gload16(Wf + (size_t)ct * 4096 + t * 8, &blds[(s * 512 + t) * 8]);
    }
    __syncthreads();

    {  // ---- xd_q -> qp ----
      const f32x4 x0 = ct_lds(blds, 0, lane, bbig[(48 + 2 * h) * 16 + cl], Ah, Al);
      const f32x4 x1 = ct_lds(blds, 1, lane, bbig[(49 + 2 * h) * 16 + cl], Ah, Al);
#pragma unroll
      for (int j = 0; j < 4; ++j) {
        float mv = fmaxf(x0[j], (cl < 14) ? x1[j] : -3.4e38f);
#pragma unroll
        for (int m = 1; m < 16; m <<= 1) mv = fmaxf(mv, __shfl_xor(mv, m));
        const float dg = h2 * dsq[j];
        const int r = rbase + 4 * g + j;
        if (r < NN) {
          float* dst = qp + (size_t)r * 120 + h * 30;
          dst[cl] = RATIO_F * (expf(x0[j] - dg - mv) + EPS_F);
          if (cl < 14) dst[16 + cl] = RATIO_F * (expf(x1[j] - dg - mv) + EPS_F);
        }
      }
    }
    {  // ---- xd_k -> kbuf + global head max ----
      const f32x4 x0 = ct_lds(blds, 2, lane, bbig[(56 + 2 * h) * 16 + cl], Ah, Al);
      const f32x4 x1 = ct_lds(blds, 3, lane, bbig[(57 + 2 * h) * 16 + cl], Ah, Al);
      float wmax = -3.4e38f;
#pragma unroll
      for (int j = 0; j < 4; ++j) {
        float mv = fmaxf(x0[j], (cl < 14) ? x1[j] : -3.4e38f);
#pragma unroll
        for (int m = 1; m < 16; m <<= 1) mv = fmaxf(mv, __shfl_xor(mv, m));
        wmax = fmaxf(wmax, mv);
        const float dg = h2 * dsk[j];
        const int r = rbase + 4 * g + j;
        if (r < NN) {
          float* dst = kbuf + (size_t)r * 120 + h * 30;
          dst[cl] = x0[j] - dg;
          if (cl < 14) dst[16 + cl] = x1[j] - dg;
        }
      }
      wmax = fmaxf(wmax, __shfl_xor(wmax, 16));
      wmax = fmaxf(wmax, __shfl_xor(wmax, 32));
      if (lane == 0) atomicMax(&kmaxU[h], fenc(wmax));
    }
  } else {
    // ---- v = z @ Wv (+bias) -> f16, col-half y-4 ----
    const int ct0 = 32 + (y - 4) * 8;
#pragma unroll
    for (int s = 0; s < 8; ++s)
      gload16(Wf + (size_t)(ct0 + s) * 4096 + t * 8, &blds[(s * 512 + t) * 8]);
    load_frags16(zin + (size_t)arow * 256, g, Ah, Al);
    __syncthreads();
#pragma unroll
    for (int c = 0; c < 8; ++c) {
      const f32x4 a = ct_lds(blds, c, lane, bbig[(ct0 + c) * 16 + cl], Ah, Al);
      const int colb = (ct0 - 32 + c) * 16 + cl;
#pragma unroll
      for (int j = 0; j < 4; ++j) {
        const int r = rbase + 4 * g + j;
        if (r < NN) vh[(size_t)r * 256 + colb] = (_Float16)a[j];
      }
    }
  }
}

// ------------- K3a: per-chunk partials of kvs/ksum (no atomics) -------------
__global__ __launch_bounds__(256)
void k3_kvs(const float* __restrict__ kbr, const _Float16* __restrict__ vh,
            const unsigned* __restrict__ kmaxU, float* __restrict__ partial) {
  __shared__ float kpch[128 * 32];
  __shared__ float vch[128 * 68];
  const int h = blockIdx.y;
  const int n0 = blockIdx.x * 128;
  const int cnt = min(128, NN - n0);
  const int t = threadIdx.x;
  const float mx = fdec(kmaxU[h]);
  const int m = t >> 3, dg = t & 7, d0 = dg * 8;
#pragma unroll
  for (int l = 0; l < 15; ++l) {
    const int flat = l * 256 + t;
    const int nl = flat / 30, mm = flat - nl * 30;
    kpch[nl * 32 + mm] = (nl < cnt)
        ? RATIO_F * (expf(kbr[(size_t)(n0 + nl) * 120 + h * 30 + mm] - mx) + EPS_F)
        : 0.f;
  }
#pragma unroll
  for (int l = 0; l < 8; ++l) {
    const int f4 = l * 256 + t;
    const int nl = f4 >> 4, dd = (f4 & 15) * 4;
    float4 vv = make_float4(0.f, 0.f, 0.f, 0.f);
    if (nl < cnt) {
      f16x4 u = *(const f16x4*)(vh + (size_t)(n0 + nl) * 256 + h * 64 + dd);
      vv = make_float4((float)u[0], (float)u[1], (float)u[2], (float)u[3]);
    }
    *(float4*)&vch[nl * 68 + dd] = vv;
  }
  __syncthreads();
  float acc[8] = {0, 0, 0, 0, 0, 0, 0, 0};
  float asum = 0.f;
  const int ms = (m < 30) ? m : 0;
  for (int nl = 0; nl < cnt; ++nl) {
    const float kv = kpch[nl * 32 + ms];
    const float4 va = *(const float4*)&vch[nl * 68 + d0];
    const float4 vb = *(const float4*)&vch[nl * 68 + d0 + 4];
    fma4(&acc[0], kv, va);
    fma4(&acc[4], kv, vb);
    asum += kv;
  }
  if (m < 30) {
    float* dst = partial + ((size_t)blockIdx.y * NCH + blockIdx.x) * 1952 + m * 64 + d0;
#pragma unroll
    for (int j = 0; j < 8; ++j) dst[j] = acc[j];
    if (dg == 0)
      partial[((size_t)blockIdx.y * NCH + blockIdx.x) * 1952 + 1920 + m] = asum;
  }
}

// ------------- K3b: reduce partials -> kvs, ksum -------------
__global__ __launch_bounds__(256)
void k3b_reduce(const float* __restrict__ partial, float* __restrict__ kvs,
                float* __restrict__ ksum) {
  const int idx = blockIdx.x * 256 + threadIdx.x;
  if (idx >= 4 * 1952) return;
  const int h = idx / 1952, q = idx - h * 1952;
  float s = 0.f;
  for (int c = 0; c < NCH; ++c)
    s += partial[((size_t)h * NCH + c) * 1952 + q];
  if (q < 1920) kvs[h * 1920 + q] = s;
  else if (q < 1950) ksum[h * 30 + (q - 1920)] = s;
}

// ------------- K4: num/den -> zbuf -------------
__global__ __launch_bounds__(256)
void k4_attn(const float* __restrict__ qp, const float* __restrict__ kvs,
             const float* __restrict__ ksum, float* __restrict__ zbuf) {
  __shared__ float kvsl[120 * 68];
  __shared__ float ksl[120];
  __shared__ float qpl[32 * 120];
  const int t = threadIdx.x;
  const int n0 = blockIdx.x * 32;
#pragma unroll
  for (int l = 0; l < 30; ++l) {
    const int f = l * 256 + t;           // 7680
    const int hm = f >> 6, d = f & 63;
    kvsl[hm * 68 + d] = kvs[f];
  }
  if (t < 120) ksl[t] = ksum[t];
#pragma unroll
  for (int l = 0; l < 15; ++l) {
    const int f = l * 256 + t;           // 3840
    qpl[f] = qp[(size_t)n0 * 120 + f];
  }
  __syncthreads();
  const int nl = t >> 3, dg = t & 7, d0 = dg * 8;
  const float* qrow = &qpl[nl * 120];
  float den[4] = {0, 0, 0, 0};
  for (int m = 0; m < 30; ++m) {
#pragma unroll
    for (int hh = 0; hh < 4; ++hh) den[hh] = fmaf(qrow[hh * 30 + m], ksl[hh * 30 + m], den[hh]);
  }
  float acc[4][8] = {};
  for (int m = 0; m < 30; ++m) {
#pragma unroll
    for (int hh = 0; hh < 4; ++hh) {
      const float qv = qrow[hh * 30 + m];
      const float* kr = &kvsl[(hh * 30 + m) * 68 + d0];
      const float4 ka = *(const float4*)kr;
      const float4 kb = *(const float4*)(kr + 4);
      fma4(&acc[hh][0], qv, ka);
      fma4(&acc[hh][4], qv, kb);
    }
  }
  const size_t n = n0 + nl;
#pragma unroll
  for (int hh = 0; hh < 4; ++hh) {
    const float inv = 1.0f / den[hh];
    float4 o1 = make_float4(acc[hh][0] * inv, acc[hh][1] * inv, acc[hh][2] * inv, acc[hh][3] * inv);
    float4 o2 = make_float4(acc[hh][4] * inv, acc[hh][5] * inv, acc[hh][6] * inv, acc[hh][7] * inv);
    *(float4*)(zbuf + n * 256 + hh * 64 + d0) = o1;
    *(float4*)(zbuf + n * 256 + hh * 64 + d0 + 4) = o2;
  }
}

// ------------- K5: degree counts (int4 vectorized) -------------
__global__ __launch_bounds__(256)
void k5_deg(const int* __restrict__ ei, int* __restrict__ dini, int* __restrict__ douti) {
  const int q = blockIdx.x * 256 + threadIdx.x;
  if (q >= EE / 4) return;
  const int4 r4 = *(const int4*)(ei + q * 4);
  const int4 c4 = *(const int4*)(ei + EE + q * 4);
  atomicAdd(&dini[c4.x], 1); atomicAdd(&dini[c4.y], 1);
  atomicAdd(&dini[c4.z], 1); atomicAdd(&dini[c4.w], 1);
  atomicAdd(&douti[r4.x], 1); atomicAdd(&douti[r4.y], 1);
  atomicAdd(&douti[r4.z], 1); atomicAdd(&douti[r4.w], 1);
}

// ------------- K6a: exclusive scan of in-degrees (1024 threads, int4) -------------
__global__ __launch_bounds__(1024)
void k6a_scan(const int* __restrict__ cnt, int* __restrict__ off) {
  __shared__ int s[1024];
  const int t = threadIdx.x;
  int4 v[5];
  int sum = 0;
  const int4* p4 = (const int4*)(cnt + t * 20);
#pragma unroll
  for (int i = 0; i < 5; ++i) {
    v[i] = p4[i];
    sum += v[i].x + v[i].y + v[i].z + v[i].w;
  }
  s[t] = sum;
  __syncthreads();
  for (int o = 1; o < 1024; o <<= 1) {
    const int add = (t >= o) ? s[t - o] : 0;
    __syncthreads();
    s[t] += add;
    __syncthreads();
  }
  int run = (t == 0) ? 0 : s[t - 1];
  if (t == 0) off[0] = 0;
  const int base = t * 20;
#pragma unroll
  for (int i = 0; i < 5; ++i) {
    const int vals[4] = {v[i].x, v[i].y, v[i].z, v[i].w};
#pragma unroll
    for (int j = 0; j < 4; ++j) {
      const int idx = base + i * 4 + j;
      if (idx < NN) { run += vals[j]; off[idx + 1] = run; }
    }
  }
}

// ------------- K6b: fill CSR (rows bucketed by col) -------------
__global__ __launch_bounds__(256)
void k6b_fill(const int* __restrict__ ei, const int* __restrict__ coff,
              int* __restrict__ cursor, int* __restrict__ crow) {
  const int e = blockIdx.x * 256 + threadIdx.x;
  const int r = ei[e], c = ei[EE + e];
  const int pos = atomicAdd(&cursor[c], 1);
  crow[coff[c] + pos] = r;
}

// ------------- K6c: rw[n] = rsqrt(out-degree) (shortens k7 dep chain) -----
__global__ __launch_bounds__(256)
void k6c_rw(const int* __restrict__ douti, float* __restrict__ rw) {
  const int n = blockIdx.x * 256 + threadIdx.x;
  if (n < NN) rw[n] = rsqrtf((float)douti[n]);
}

// ------------- K7: gather relational bias; one wave per node -------------
__global__ __launch_bounds__(256)
void k7_gather(const int* __restrict__ coff, const int* __restrict__ crow,
               const float* __restrict__ rw, const _Float16* __restrict__ vh,
               const float* __restrict__ bp, float* __restrict__ zbuf) {
  const int node = blockIdx.x * 4 + (threadIdx.x >> 6);
  const int lane = threadIdx.x & 63;
  const int o0 = coff[node], o1 = coff[node + 1];
  float a0 = 0.f, a1 = 0.f, a2 = 0.f, a3 = 0.f;
  if (o1 > o0) {
    int e = o0;
    for (; e + 8 <= o1; e += 8) {
      int rr[8];
#pragma unroll
      for (int u = 0; u < 8; ++u) rr[u] = crow[e + u];
      float ww[8];
#pragma unroll
      for (int u = 0; u < 8; ++u) ww[u] = rw[rr[u]];
#pragma unroll
      for (int u = 0; u < 8; ++u) {
        const f16x4 vv = *(const f16x4*)(vh + (size_t)rr[u] * 256 + lane * 4);
        a0 = fmaf(ww[u], (float)vv[0], a0);
        a1 = fmaf(ww[u], (float)vv[1], a1);
        a2 = fmaf(ww[u], (float)vv[2], a2);
        a3 = fmaf(ww[u], (float)vv[3], a3);
      }
    }
    for (; e < o1; ++e) {
      const int r = crow[e];
      const float wr = rw[r];
      const f16x4 vv = *(const f16x4*)(vh + (size_t)r * 256 + lane * 4);
      a0 = fmaf(wr, (float)vv[0], a0);
      a1 = fmaf(wr, (float)vv[1], a1);
      a2 = fmaf(wr, (float)vv[2], a2);
      a3 = fmaf(wr, (float)vv[3], a3);
    }
    const float rin = rsqrtf((float)(o1 - o0));
    a0 *= rin; a1 *= rin; a2 *= rin; a3 *= rin;
  }
  const float sg = 1.f / (1.f + expf(-bp[lane >> 4]));   // head = (lane*4)>>6
  float* dst = zbuf + (size_t)node * 256 + lane * 4;
  const float4 old = *(const float4*)dst;
  *(float4*)dst = make_float4(old.x + sg * a0, old.y + sg * a1,
                              old.z + sg * a2, old.w + sg * a3);
}

// ------------- K8: out = zbuf @ Wo^T + bo -------------
__global__ __launch_bounds__(256)
void k8_out(const float* __restrict__ zbuf, const float* __restrict__ Wo,
            const float* __restrict__ bo, float* __restrict__ out) {
  __shared__ float WoT[256 * 33];
  __shared__ float zbl[8 * 256];
  const int t = threadIdx.x;
  const int ch = blockIdx.y;  // 0/1 -> output cols [ch*32, ch*32+32)
#pragma unroll
  for (int l = 0; l < 32; ++l) {
    WoT[t * 33 + l] = Wo[(ch * 32 + l) * 256 + t];
  }
  const int nl = t >> 5, cp = t & 31;
  const float bias = bo[ch * 32 + cp];
  for (int g = blockIdx.x; g < 2500; g += gridDim.x) {
    __syncthreads();
#pragma unroll
    for (int l = 0; l < 2; ++l) {
      const int f4 = l * 256 + t;
      *(float4*)&zbl[f4 * 4] = *(const float4*)(zbuf + (size_t)g * 2048 + f4 * 4);
    }
    __syncthreads();
    float acc = bias;
#pragma unroll
    for (int i4 = 0; i4 < 64; ++i4) {
      const float4 z4 = *(const float4*)&zbl[nl * 256 + i4 * 4];
      acc = fmaf(z4.x, WoT[(i4 * 4 + 0) * 33 + cp], acc);
      acc = fmaf(z4.y, WoT[(i4 * 4 + 1) * 33 + cp], acc);
      acc = fmaf(z4.z, WoT[(i4 * 4 + 2) * 33 + cp], acc);
      acc = fmaf(z4.w, WoT[(i4 * 4 + 3) * 33 + cp], acc);
    }
    out[((size_t)g * 8 + nl) * 64 + ch * 32 + cp] = acc;
  }
}

extern "C" void kernel_launch(void* const* d_in, const int* in_sizes, int n_in,
                              void* d_out, int out_size, void* d_ws, size_t ws_size,
                              hipStream_t stream) {
  (void)in_sizes; (void)n_in; (void)out_size; (void)ws_size;
  const float* z    = (const float*)d_in[0];
  const float* feat = (const float*)d_in[1];
  const int*   ei   = (const int*)d_in[2];
  const float* tau  = (const float*)d_in[3];
  const float* Wq_w = (const float*)d_in[4];
  const float* Wq_b = (const float*)d_in[5];
  const float* Wk_w = (const float*)d_in[6];
  const float* Wk_b = (const float*)d_in[7];
  const float* Wv_w = (const float*)d_in[8];
  const float* Wv_b = (const float*)d_in[9];
  const float* Wo_w = (const float*)d_in[10];
  const float* Wo_b = (const float*)d_in[11];
  const float* bp   = (const float*)d_in[12];
  const float* proj = (const float*)d_in[13];
  float* out = (float*)d_out;

  char* p = (char*)d_ws;
  auto alloc = [&](size_t bytes) { char* r = p; p += (bytes + 255) & ~(size_t)255; return r; };
  _Float16* Wf    = (_Float16*)alloc((size_t)256 * 1024 * 2);
  float*    bbig  = (float*)alloc(1024 * 4);
  _Float16* vh    = (_Float16*)alloc((size_t)NN * 256 * 2);
  float*    qp    = (float*)alloc((size_t)NN * 120 * 4);
  float*    kbuf  = (float*)alloc((size_t)NN * 120 * 4);
  float*    zbuf  = (float*)alloc((size_t)NN * 256 * 4);
  float*    partial = (float*)alloc((size_t)4 * NCH * 1952 * 4);
  float*    kvs   = (float*)alloc(7680 * 4);
  float*    ksum  = (float*)alloc(120 * 4);
  float*    rw    = (float*)alloc((size_t)NN * 4);
  // ---- contiguous zero-region ----
  char* z0 = p;
  unsigned* kmaxU = (unsigned*)alloc(16);
  int*      dini  = (int*)alloc((size_t)20480 * 4);   // padded for int4 scan
  int*      douti = (int*)alloc((size_t)NN * 4);
  int*      cursor= (int*)alloc((size_t)NN * 4);
  char* z1 = p;
  int*      coff  = (int*)alloc((size_t)(NN + 1) * 4);
  int*      crow  = (int*)alloc((size_t)EE * 4);

  hipMemsetAsync(z0, 0, (size_t)(z1 - z0), stream);

  k0_build<<<1024, 256, 0, stream>>>(Wq_w, Wk_w, Wv_w, Wq_b, Wk_b, Wv_b, proj, tau, Wf, bbig);
  k5_deg<<<(EE / 4 + 255) / 256, 256, 0, stream>>>(ei, dini, douti);
  k6a_scan<<<1, 1024, 0, stream>>>(dini, coff);
  k6b_fill<<<EE / 256, 256, 0, stream>>>(ei, coff, cursor, crow);
  k6c_rw<<<(NN + 255) / 256, 256, 0, stream>>>(douti, rw);
  k1_all<<<dim3(157, 6), 512, 0, stream>>>(feat, z, Wf, bbig, tau, qp, kbuf, vh, kmaxU);
  k3_kvs<<<dim3(NCH, 4), 256, 0, stream>>>(kbuf, vh, kmaxU, partial);
  k3b_reduce<<<(4 * 1952 + 255) / 256, 256, 0, stream>>>(partial, kvs, ksum);
  k4_attn<<<NN / 32, 256, 0, stream>>>(qp, kvs, ksum, zbuf);
  k7_gather<<<NN / 4, 256, 0, stream>>>(coff, crow, rw, vh, bp, zbuf);
  k8_out<<<dim3(512, 2), 256, 0, stream>>>(zbuf, Wo_w, Wo_b, out);
}